// Round 1
// baseline (2487.483 us; speedup 1.0000x reference)
//
#include <hip/hip_runtime.h>
#include <hip/hip_bf16.h>
#include <math.h>

#define BB  2
#define TT  2048
#define DDE 1024
#define NHH 16
#define HDD 64

// ---------------------------------------------------------------------------
// GEMM: C[M,N] = A[M,K] * W[N,K]^T + bmul * bias[N]
// 128x128 tile, 256 threads, 8x8 micro-tile per thread, BK=16.
// ---------------------------------------------------------------------------
__global__ __launch_bounds__(256) void gemm_nt_bias(
    const float* __restrict__ A, const float* __restrict__ W,
    const float* __restrict__ bias, float* __restrict__ C,
    int M, int N, int K, float bmul)
{
    __shared__ float As[16][128];   // [k][m]
    __shared__ float Ws[16][128];   // [k][n]
    const int tid = threadIdx.x;
    const int bm  = blockIdx.y * 128;
    const int bn  = blockIdx.x * 128;
    const int tm  = tid & 15;
    const int tn  = tid >> 4;
    const int lr  = tid >> 1;        // 0..127
    const int lk  = (tid & 1) * 8;   // 0 or 8

    float acc[8][8];
    #pragma unroll
    for (int i = 0; i < 8; ++i)
        #pragma unroll
        for (int j = 0; j < 8; ++j) acc[i][j] = 0.f;

    const float* ap = A + (size_t)(bm + lr) * K + lk;
    const float* wp = W + (size_t)(bn + lr) * K + lk;

    for (int k0 = 0; k0 < K; k0 += 16) {
        float4 a0 = *(const float4*)(ap + k0);
        float4 a1 = *(const float4*)(ap + k0 + 4);
        float4 w0 = *(const float4*)(wp + k0);
        float4 w1 = *(const float4*)(wp + k0 + 4);
        As[lk+0][lr] = a0.x; As[lk+1][lr] = a0.y; As[lk+2][lr] = a0.z; As[lk+3][lr] = a0.w;
        As[lk+4][lr] = a1.x; As[lk+5][lr] = a1.y; As[lk+6][lr] = a1.z; As[lk+7][lr] = a1.w;
        Ws[lk+0][lr] = w0.x; Ws[lk+1][lr] = w0.y; Ws[lk+2][lr] = w0.z; Ws[lk+3][lr] = w0.w;
        Ws[lk+4][lr] = w1.x; Ws[lk+5][lr] = w1.y; Ws[lk+6][lr] = w1.z; Ws[lk+7][lr] = w1.w;
        __syncthreads();
        #pragma unroll
        for (int kk = 0; kk < 16; ++kk) {
            float a[8], w[8];
            #pragma unroll
            for (int i = 0; i < 8; ++i) a[i] = As[kk][tm + 16*i];
            #pragma unroll
            for (int j = 0; j < 8; ++j) w[j] = Ws[kk][tn + 16*j];
            #pragma unroll
            for (int i = 0; i < 8; ++i)
                #pragma unroll
                for (int j = 0; j < 8; ++j)
                    acc[i][j] += a[i] * w[j];
        }
        __syncthreads();
    }
    #pragma unroll
    for (int j = 0; j < 8; ++j) {
        const int n  = bn + tn + 16*j;
        const float bj = bias[n] * bmul;
        #pragma unroll
        for (int i = 0; i < 8; ++i)
            C[(size_t)(bm + tm + 16*i) * N + n] = acc[i][j] + bj;
    }
}

// ---------------------------------------------------------------------------
// Kernel A: causal softmax attention.  y_ar[b,t,h*64+d]
// block = 256 threads, one block per (q-tile 64, head, batch).
// LDS layouts chosen for conflict-free reads:
//   Qt[d][q], KV as K:[d][k] then V:[k][d], Pt[k][q].
// ---------------------------------------------------------------------------
__global__ __launch_bounds__(256) void attn_ar_kernel(
    const float* __restrict__ qk, const float* __restrict__ x,
    float* __restrict__ y_ar)
{
    const int qt  = blockIdx.x;
    const int h   = blockIdx.y;
    const int b   = blockIdx.z;
    const int tid = threadIdx.x;
    const int q0  = qt * 64;
    const int tm  = tid & 15;
    const int tn  = tid >> 4;

    __shared__ __align__(16) float Qt[64][64];   // [d][q]
    __shared__ __align__(16) float KV[64][64];   // K: [d][k]; V: [k][d]
    __shared__ __align__(16) float Pt[64][64];   // [k][q]
    __shared__ float row_alpha[64];
    __shared__ float row_scale[64];

    // load Q tile transposed: Qt[d][q]
    {
        const float* qbase = qk + ((size_t)(b*TT + q0)) * (2*DDE) + h*HDD;
        #pragma unroll
        for (int it = 0; it < 4; ++it) {
            int f = tid + it*256;
            int row = f >> 4, d0 = (f & 15) * 4;
            float4 v = *(const float4*)(qbase + (size_t)row * (2*DDE) + d0);
            Qt[d0+0][row] = v.x; Qt[d0+1][row] = v.y;
            Qt[d0+2][row] = v.z; Qt[d0+3][row] = v.w;
        }
    }

    float acc[4][4];
    #pragma unroll
    for (int i = 0; i < 4; ++i)
        #pragma unroll
        for (int j = 0; j < 4; ++j) acc[i][j] = 0.f;
    float m_r = -1e30f, l_r = 0.f;

    for (int kt = 0; kt <= qt; ++kt) {
        const int s0 = kt * 64;
        __syncthreads();   // protect KV reuse from previous PV
        {   // load K tile transposed: KV[d][k]
            const float* kbase = qk + ((size_t)(b*TT + s0)) * (2*DDE) + DDE + h*HDD;
            #pragma unroll
            for (int it = 0; it < 4; ++it) {
                int f = tid + it*256;
                int row = f >> 4, d0 = (f & 15) * 4;
                float4 v = *(const float4*)(kbase + (size_t)row * (2*DDE) + d0);
                KV[d0+0][row] = v.x; KV[d0+1][row] = v.y;
                KV[d0+2][row] = v.z; KV[d0+3][row] = v.w;
            }
        }
        __syncthreads();
        // S = Q K^T
        float sv[4][4];
        #pragma unroll
        for (int i = 0; i < 4; ++i)
            #pragma unroll
            for (int j = 0; j < 4; ++j) sv[i][j] = 0.f;
        for (int dd = 0; dd < 64; ++dd) {
            float a[4], kq[4];
            #pragma unroll
            for (int i = 0; i < 4; ++i) a[i]  = Qt[dd][tm + 16*i];
            #pragma unroll
            for (int j = 0; j < 4; ++j) kq[j] = KV[dd][tn + 16*j];
            #pragma unroll
            for (int i = 0; i < 4; ++i)
                #pragma unroll
                for (int j = 0; j < 4; ++j)
                    sv[i][j] += a[i] * kq[j];
        }
        // mask + scale, store transposed Pt[k][q]
        #pragma unroll
        for (int i = 0; i < 4; ++i)
            #pragma unroll
            for (int j = 0; j < 4; ++j) {
                int qg = q0 + tm + 16*i;
                int kg = s0 + tn + 16*j;
                Pt[tn + 16*j][tm + 16*i] = (kg <= qg) ? sv[i][j] * 0.125f : -1e30f;
            }
        __syncthreads();
        // online softmax, one thread per q row
        if (tid < 64) {
            float tmax = -1e30f;
            for (int kk = 0; kk < 64; ++kk) tmax = fmaxf(tmax, Pt[kk][tid]);
            float m_new = fmaxf(m_r, tmax);
            float alpha = __expf(m_r - m_new);
            float sum = 0.f;
            for (int kk = 0; kk < 64; ++kk) {
                float p = __expf(Pt[kk][tid] - m_new);
                Pt[kk][tid] = p;
                sum += p;
            }
            l_r = l_r * alpha + sum;
            m_r = m_new;
            row_alpha[tid] = alpha;
        }
        __syncthreads();
        {   // load V tile natural: KV[k][d]   (v = heads(x))
            const float* vbase = x + ((size_t)(b*TT + s0)) * DDE + h*HDD;
            #pragma unroll
            for (int it = 0; it < 4; ++it) {
                int f = tid + it*256;
                int row = f >> 4, d0 = (f & 15) * 4;
                float4 v = *(const float4*)(vbase + (size_t)row * DDE + d0);
                *(float4*)&KV[row][d0] = v;
            }
        }
        __syncthreads();
        // O = alpha*O + P V
        #pragma unroll
        for (int i = 0; i < 4; ++i) {
            float al = row_alpha[tm + 16*i];
            #pragma unroll
            for (int j = 0; j < 4; ++j) acc[i][j] *= al;
        }
        for (int kk = 0; kk < 64; ++kk) {
            float p[4], vv[4];
            #pragma unroll
            for (int i = 0; i < 4; ++i) p[i]  = Pt[kk][tm + 16*i];
            #pragma unroll
            for (int j = 0; j < 4; ++j) vv[j] = KV[kk][tn + 16*j];
            #pragma unroll
            for (int i = 0; i < 4; ++i)
                #pragma unroll
                for (int j = 0; j < 4; ++j)
                    acc[i][j] += p[i] * vv[j];
        }
    }
    if (tid < 64) row_scale[tid] = 1.f / l_r;
    __syncthreads();
    #pragma unroll
    for (int i = 0; i < 4; ++i) {
        float sc = row_scale[tm + 16*i];
        #pragma unroll
        for (int j = 0; j < 4; ++j) {
            size_t idx = ((size_t)(b*TT + q0 + tm + 16*i)) * DDE + h*HDD + tn + 16*j;
            y_ar[idx] = acc[i][j] * sc;
        }
    }
}

// ---------------------------------------------------------------------------
// Kernel B: ARMA branch (causal attention, no softmax) fused with y_sum.
// out_ma[t] = sum_{s=1..t} dot(qa(q[t]), ka(k2[s-1])) * (v[s] - y_ar[s-1])
// y_sum[t]  = y_ar[t] + out_ma[t]
// ---------------------------------------------------------------------------
__global__ __launch_bounds__(256) void attn_ma_kernel(
    const float* __restrict__ qk, const float* __restrict__ k2b,
    const float* __restrict__ x,  const float* __restrict__ y_ar,
    float* __restrict__ y_sum)
{
    const int qt  = blockIdx.x;
    const int h   = blockIdx.y;
    const int b   = blockIdx.z;
    const int tid = threadIdx.x;
    const int q0  = qt * 64;
    const int tm  = tid & 15;
    const int tn  = tid >> 4;

    __shared__ __align__(16) float Qt[64][64];   // qa, [d][q]
    __shared__ __align__(16) float KV[64][64];   // ka: [d][s]; E: [s][d]
    __shared__ __align__(16) float Pt[64][64];   // [s][q]

    // load Q tile with qa transform, transposed
    {
        const float* qbase = qk + ((size_t)(b*TT + q0)) * (2*DDE) + h*HDD;
        #pragma unroll
        for (int it = 0; it < 4; ++it) {
            int f = tid + it*256;
            int row = f >> 4, d0 = (f & 15) * 4;
            float4 v = *(const float4*)(qbase + (size_t)row * (2*DDE) + d0);
            float z0 = v.x*0.125f, z1 = v.y*0.125f, z2 = v.z*0.125f, z3 = v.w*0.125f;
            Qt[d0+0][row] = (z0 > 0.f) ? 0.02f*z0 : z0;
            Qt[d0+1][row] = (z1 > 0.f) ? 0.02f*z1 : z1;
            Qt[d0+2][row] = (z2 > 0.f) ? 0.02f*z2 : z2;
            Qt[d0+3][row] = (z3 > 0.f) ? 0.02f*z3 : z3;
        }
    }

    float acc[4][4];
    #pragma unroll
    for (int i = 0; i < 4; ++i)
        #pragma unroll
        for (int j = 0; j < 4; ++j) acc[i][j] = 0.f;

    for (int kt = 0; kt <= qt; ++kt) {
        const int s0 = kt * 64;
        __syncthreads();
        {   // load K2 tile with sigmoid transform, transposed: KV[d][s]
            #pragma unroll
            for (int it = 0; it < 4; ++it) {
                int f = tid + it*256;
                int row = f >> 4, d0 = (f & 15) * 4;
                int s = s0 + row;
                float k0 = 0.f, k1 = 0.f, k2v = 0.f, k3 = 0.f;
                if (s >= 1) {
                    float4 v = *(const float4*)(k2b + ((size_t)(b*TT + s-1)) * DDE + h*HDD + d0);
                    k0 = 1.f/(1.f + __expf(-v.x*0.0025f));
                    k1 = 1.f/(1.f + __expf(-v.y*0.0025f));
                    k2v= 1.f/(1.f + __expf(-v.z*0.0025f));
                    k3 = 1.f/(1.f + __expf(-v.w*0.0025f));
                }
                KV[d0+0][row] = k0; KV[d0+1][row] = k1;
                KV[d0+2][row] = k2v; KV[d0+3][row] = k3;
            }
        }
        __syncthreads();
        // S = qa . ka^T
        float sv[4][4];
        #pragma unroll
        for (int i = 0; i < 4; ++i)
            #pragma unroll
            for (int j = 0; j < 4; ++j) sv[i][j] = 0.f;
        for (int dd = 0; dd < 64; ++dd) {
            float a[4], kq[4];
            #pragma unroll
            for (int i = 0; i < 4; ++i) a[i]  = Qt[dd][tm + 16*i];
            #pragma unroll
            for (int j = 0; j < 4; ++j) kq[j] = KV[dd][tn + 16*j];
            #pragma unroll
            for (int i = 0; i < 4; ++i)
                #pragma unroll
                for (int j = 0; j < 4; ++j)
                    sv[i][j] += a[i] * kq[j];
        }
        #pragma unroll
        for (int i = 0; i < 4; ++i)
            #pragma unroll
            for (int j = 0; j < 4; ++j) {
                int tg = q0 + tm + 16*i;
                int sg = s0 + tn + 16*j;
                Pt[tn + 16*j][tm + 16*i] = (sg >= 1 && sg <= tg) ? sv[i][j] : 0.f;
            }
        __syncthreads();
        {   // load E tile natural: KV[s][d] = v[s] - y_ar[s-1]
            #pragma unroll
            for (int it = 0; it < 4; ++it) {
                int f = tid + it*256;
                int row = f >> 4, d0 = (f & 15) * 4;
                int s = s0 + row;
                float4 e = make_float4(0.f, 0.f, 0.f, 0.f);
                if (s >= 1) {
                    float4 vx = *(const float4*)(x    + ((size_t)(b*TT + s  )) * DDE + h*HDD + d0);
                    float4 vy = *(const float4*)(y_ar + ((size_t)(b*TT + s-1)) * DDE + h*HDD + d0);
                    e.x = vx.x - vy.x; e.y = vx.y - vy.y;
                    e.z = vx.z - vy.z; e.w = vx.w - vy.w;
                }
                *(float4*)&KV[row][d0] = e;
            }
        }
        __syncthreads();
        // O += P E
        for (int kk = 0; kk < 64; ++kk) {
            float p[4], vv[4];
            #pragma unroll
            for (int i = 0; i < 4; ++i) p[i]  = Pt[kk][tm + 16*i];
            #pragma unroll
            for (int j = 0; j < 4; ++j) vv[j] = KV[kk][tn + 16*j];
            #pragma unroll
            for (int i = 0; i < 4; ++i)
                #pragma unroll
                for (int j = 0; j < 4; ++j)
                    acc[i][j] += p[i] * vv[j];
        }
    }
    #pragma unroll
    for (int i = 0; i < 4; ++i)
        #pragma unroll
        for (int j = 0; j < 4; ++j) {
            size_t idx = ((size_t)(b*TT + q0 + tm + 16*i)) * DDE + h*HDD + tn + 16*j;
            y_sum[idx] = y_ar[idx] + acc[i][j];
        }
}

// ---------------------------------------------------------------------------
extern "C" void kernel_launch(void* const* d_in, const int* in_sizes, int n_in,
                              void* d_out, int out_size, void* d_ws, size_t ws_size,
                              hipStream_t stream)
{
    const float* x      = (const float*)d_in[0];
    const float* w_attn = (const float*)d_in[1];
    const float* b_attn = (const float*)d_in[2];
    const float* w_k2   = (const float*)d_in[3];
    const float* b_k2   = (const float*)d_in[4];
    const float* w_proj = (const float*)d_in[5];
    const float* b_proj = (const float*)d_in[6];
    float* out = (float*)d_out;

    float* ws     = (float*)d_ws;
    float* qk_buf = ws;                               // B*T*2D
    float* k2_buf = qk_buf + (size_t)BB*TT*2*DDE;     // B*T*D
    float* y_ar   = k2_buf + (size_t)BB*TT*DDE;       // B*T*D
    float* y_sum  = y_ar   + (size_t)BB*TT*DDE;       // B*T*D

    const int M = BB*TT;
    dim3 blk(256);

    dim3 g1(2*DDE/128, M/128);
    gemm_nt_bias<<<g1, blk, 0, stream>>>(x, w_attn, b_attn, qk_buf, M, 2*DDE, DDE, 1.f);

    dim3 g2(DDE/128, M/128);
    gemm_nt_bias<<<g2, blk, 0, stream>>>(x, w_k2, b_k2, k2_buf, M, DDE, DDE, 1.f);

    dim3 ga(TT/64, NHH, BB);
    attn_ar_kernel<<<ga, blk, 0, stream>>>(qk_buf, x, y_ar);
    attn_ma_kernel<<<ga, blk, 0, stream>>>(qk_buf, k2_buf, x, y_ar, y_sum);

    gemm_nt_bias<<<g2, blk, 0, stream>>>(y_sum, w_proj, b_proj, out, M, DDE, DDE, 2.f);
}

// Round 2
// 484.682 us; speedup vs baseline: 5.1322x; 5.1322x over previous
//
#include <hip/hip_runtime.h>
#include <hip/hip_bf16.h>
#include <math.h>

#define BB  2
#define TT  2048
#define DDE 1024
#define NHH 16
#define HDD 64

typedef __bf16 bf16_t;
typedef __attribute__((ext_vector_type(8))) __bf16 bf16x8;
typedef __attribute__((ext_vector_type(4))) __bf16 bf16x4;
typedef __attribute__((ext_vector_type(4))) float  f32x4;

#define MFMA(a, b, c) __builtin_amdgcn_mfma_f32_16x16x32_bf16((a), (b), (c), 0, 0, 0)

__device__ inline unsigned short bf2us(bf16_t x) {
    union { bf16_t h; unsigned short u; } c; c.h = x; return c.u;
}

// async global->LDS, 16B per lane; LDS dest = wave-uniform base + lane*16
__device__ inline void gll16(const bf16_t* g, unsigned short* l) {
    __builtin_amdgcn_global_load_lds(
        (const __attribute__((address_space(1))) void*)g,
        (__attribute__((address_space(3))) void*)l, 16, 0, 0);
}

// ---------------------------------------------------------------------------
// fp32 -> bf16 conversion (memory-bound, float4 in / bf16x4 out)
// ---------------------------------------------------------------------------
__global__ __launch_bounds__(256) void cvt_f32_bf16(
    const float* __restrict__ in, bf16_t* __restrict__ out, int n)
{
    int i = (blockIdx.x * 256 + threadIdx.x) * 4;
    if (i < n) {
        float4 v = *(const float4*)(in + i);
        bf16x4 o;
        o[0] = (bf16_t)v.x; o[1] = (bf16_t)v.y;
        o[2] = (bf16_t)v.z; o[3] = (bf16_t)v.w;
        *(bf16x4*)(out + i) = o;
    }
}

// ---------------------------------------------------------------------------
// bf16 MFMA GEMM (m97 structure): C[M,N] = A[M,K] * W[N,K]^T + bmul*bias[N]
// 128x128 tile, 4 waves, BK=32, global_load_lds width=16.
// ---------------------------------------------------------------------------
template<int OUT_BF16>
__global__ __launch_bounds__(256) void gemm_bf16(
    const bf16_t* __restrict__ A, const bf16_t* __restrict__ W,
    const float* __restrict__ bias, void* __restrict__ Cout,
    int M, int N, int K, float bmul)
{
    __shared__ __align__(16) unsigned short As[128 * 32];
    __shared__ __align__(16) unsigned short Bs[128 * 32];
    const int tid  = threadIdx.x;
    const int wave = tid >> 6, lane = tid & 63;
    const int l15  = lane & 15, quad = lane >> 4;
    const int bm = blockIdx.y * 128, bn = blockIdx.x * 128;
    const int wm = (wave & 1) * 64, wn = (wave >> 1) * 64;

    f32x4 acc[4][4];
    #pragma unroll
    for (int i = 0; i < 4; ++i)
        #pragma unroll
        for (int j = 0; j < 4; ++j) acc[i][j] = (f32x4)0.f;

    const int srow = wave * 32 + (lane >> 2);   // staging row (issue 0)
    const int skof = (lane & 3) * 8;            // staging k offset (elems)
    const bf16_t* ga = A + (size_t)(bm + srow) * K + skof;
    const bf16_t* gw = W + (size_t)(bn + srow) * K + skof;
    unsigned short* la = As + wave * 1024 + lane * 8;
    unsigned short* lb = Bs + wave * 1024 + lane * 8;

    for (int k0 = 0; k0 < K; k0 += 32) {
        __syncthreads();
        gll16(ga + k0,                 la);
        gll16(ga + k0 + (size_t)16*K,  la + 512);
        gll16(gw + k0,                 lb);
        gll16(gw + k0 + (size_t)16*K,  lb + 512);
        __syncthreads();
        bf16x8 af[4], bfr[4];
        #pragma unroll
        for (int mt = 0; mt < 4; ++mt)
            af[mt] = *(const bf16x8*)(As + (wm + mt*16 + l15) * 32 + quad * 8);
        #pragma unroll
        for (int nt = 0; nt < 4; ++nt)
            bfr[nt] = *(const bf16x8*)(Bs + (wn + nt*16 + l15) * 32 + quad * 8);
        #pragma unroll
        for (int mt = 0; mt < 4; ++mt)
            #pragma unroll
            for (int nt = 0; nt < 4; ++nt)
                acc[mt][nt] = MFMA(af[mt], bfr[nt], acc[mt][nt]);
    }

    #pragma unroll
    for (int nt = 0; nt < 4; ++nt) {
        const int col = bn + wn + nt*16 + l15;
        const float bj = bias[col] * bmul;
        #pragma unroll
        for (int mt = 0; mt < 4; ++mt)
            #pragma unroll
            for (int r = 0; r < 4; ++r) {
                const int row = bm + wm + mt*16 + quad*4 + r;
                const float v = acc[mt][nt][r] + bj;
                if (OUT_BF16) ((bf16_t*)Cout)[(size_t)row * N + col] = (bf16_t)v;
                else          ((float*)Cout)[(size_t)row * N + col]  = v;
            }
    }
}

// ---------------------------------------------------------------------------
// AR: flash causal softmax attention with MFMA. One block = (64 q, head, batch).
// Q/K staged via global_load_lds with XOR-swizzled source chunks (bank-even).
// V^T and P staged via VGPR with +8-elem row padding (stride 72).
// ---------------------------------------------------------------------------
__global__ __launch_bounds__(256) void attn_ar_mfma(
    const bf16_t* __restrict__ qkb, const bf16_t* __restrict__ xb,
    bf16_t* __restrict__ yarb)
{
    const int qt = blockIdx.x, h = blockIdx.y, b = blockIdx.z;
    const int tid = threadIdx.x, wave = tid >> 6, lane = tid & 63;
    const int l15 = lane & 15, quad = lane >> 4;
    const int q0 = qt * 64;

    __shared__ __align__(16) unsigned short Qs[64 * 64];   // [q][d], chunk-swizzled
    __shared__ __align__(16) unsigned short Ks[64 * 64];   // [s][d], chunk-swizzled
    __shared__ __align__(16) unsigned short Vt[64 * 72];   // [d][s], padded
    __shared__ __align__(16) unsigned short Pw[4][16 * 72];// per-wave P [q][s], padded

    {   // stage Q (gll, swizzled source chunk = (lane&7) ^ row&7)
        const int r8 = lane >> 3;
        const int ck = (lane & 7) ^ r8;
        const bf16_t* qg = qkb + (size_t)(b*TT + q0 + wave*16 + r8) * (2*DDE) + h*HDD + ck*8;
        unsigned short* qd = Qs + wave * 1024 + lane * 8;
        gll16(qg, qd);
        gll16(qg + (size_t)8 * (2*DDE), qd + 512);
    }

    f32x4 o[4];
    #pragma unroll
    for (int nt = 0; nt < 4; ++nt) o[nt] = (f32x4)0.f;
    float mrow[4], lrow[4], al[4];
    #pragma unroll
    for (int r = 0; r < 4; ++r) { mrow[r] = -1e30f; lrow[r] = 0.f; }
    const int ql_tile = 16*wave + quad*4;

    for (int kt = 0; kt <= qt; ++kt) {
        const int s0 = kt * 64;
        __syncthreads();
        {   // stage K (gll, swizzled)
            const int r8 = lane >> 3;
            const int ck = (lane & 7) ^ r8;
            const bf16_t* kg = qkb + (size_t)(b*TT + s0 + wave*16 + r8) * (2*DDE) + DDE + h*HDD + ck*8;
            unsigned short* kd = Ks + wave * 1024 + lane * 8;
            gll16(kg, kd);
            gll16(kg + (size_t)8 * (2*DDE), kd + 512);
        }
        {   // stage V^T (gather 4 s at fixed d, write b64)
            const int d = tid & 63, sb0 = (tid >> 6) * 4;
            #pragma unroll
            for (int j = 0; j < 4; ++j) {
                const int sb = sb0 + j*16;
                unsigned long long w = 0;
                #pragma unroll
                for (int u = 0; u < 4; ++u) {
                    unsigned short t = ((const unsigned short*)xb)[(size_t)(b*TT + s0 + sb + u)*DDE + h*HDD + d];
                    w |= (unsigned long long)t << (16*u);
                }
                *(unsigned long long*)(Vt + d*72 + sb) = w;
            }
        }
        __syncthreads();

        // S = Q K^T  (wave computes its 16 q rows x 64 s)
        const int ckA0 = (quad    ) ^ (l15 & 7);
        const int ckA1 = (quad + 4) ^ (l15 & 7);
        bf16x8 qa0 = *(const bf16x8*)(Qs + (16*wave + l15)*64 + ckA0*8);
        bf16x8 qa1 = *(const bf16x8*)(Qs + (16*wave + l15)*64 + ckA1*8);
        f32x4 sv[4];
        #pragma unroll
        for (int nt = 0; nt < 4; ++nt) {
            const unsigned short* kr = Ks + (nt*16 + l15)*64;
            bf16x8 kb0 = *(const bf16x8*)(kr + ckA0*8);
            bf16x8 kb1 = *(const bf16x8*)(kr + ckA1*8);
            f32x4 z = (f32x4)0.f;
            z = MFMA(qa0, kb0, z);
            z = MFMA(qa1, kb1, z);
            sv[nt] = z;
        }
        // scale + causal mask (only diagonal tile needs element masking)
        const bool diag = (kt == qt);
        #pragma unroll
        for (int nt = 0; nt < 4; ++nt)
            #pragma unroll
            for (int r = 0; r < 4; ++r) {
                float v = sv[nt][r] * 0.125f;
                if (diag) { const int sl = nt*16 + l15; if (sl > ql_tile + r) v = -1e30f; }
                sv[nt][r] = v;
            }
        // online softmax: row stats via shfl over the 16-lane group
        float mnew[4];
        #pragma unroll
        for (int r = 0; r < 4; ++r) {
            float mx = fmaxf(fmaxf(sv[0][r], sv[1][r]), fmaxf(sv[2][r], sv[3][r]));
            mx = fmaxf(mx, __shfl_xor(mx, 1));
            mx = fmaxf(mx, __shfl_xor(mx, 2));
            mx = fmaxf(mx, __shfl_xor(mx, 4));
            mx = fmaxf(mx, __shfl_xor(mx, 8));
            mnew[r] = fmaxf(mrow[r], mx);
            al[r] = __expf(mrow[r] - mnew[r]);
            mrow[r] = mnew[r];
        }
        #pragma unroll
        for (int r = 0; r < 4; ++r) {
            float sm = 0.f;
            #pragma unroll
            for (int nt = 0; nt < 4; ++nt) {
                float p = __expf(sv[nt][r] - mnew[r]);
                sv[nt][r] = p;
                sm += p;
            }
            sm += __shfl_xor(sm, 1);
            sm += __shfl_xor(sm, 2);
            sm += __shfl_xor(sm, 4);
            sm += __shfl_xor(sm, 8);
            lrow[r] = lrow[r] * al[r] + sm;
        }
        // P -> wave-private LDS (bf16, padded)
        unsigned short* pw = Pw[wave];
        #pragma unroll
        for (int r = 0; r < 4; ++r)
            #pragma unroll
            for (int nt = 0; nt < 4; ++nt)
                pw[(quad*4 + r)*72 + nt*16 + l15] = bf2us((bf16_t)sv[nt][r]);

        // O = diag(alpha) O + P V
        #pragma unroll
        for (int nt = 0; nt < 4; ++nt)
            #pragma unroll
            for (int r = 0; r < 4; ++r) o[nt][r] *= al[r];
        bf16x8 pa0 = *(const bf16x8*)(pw + l15*72 + quad*8);
        bf16x8 pa1 = *(const bf16x8*)(pw + l15*72 + 32 + quad*8);
        #pragma unroll
        for (int nt = 0; nt < 4; ++nt) {
            const unsigned short* vr = Vt + (nt*16 + l15)*72;
            bf16x8 vb0 = *(const bf16x8*)(vr + quad*8);
            bf16x8 vb1 = *(const bf16x8*)(vr + 32 + quad*8);
            o[nt] = MFMA(pa0, vb0, o[nt]);
            o[nt] = MFMA(pa1, vb1, o[nt]);
        }
    }

    #pragma unroll
    for (int nt = 0; nt < 4; ++nt) {
        const int col = h*HDD + nt*16 + l15;
        #pragma unroll
        for (int r = 0; r < 4; ++r) {
            const int row = q0 + 16*wave + quad*4 + r;
            yarb[(size_t)(b*TT + row)*DDE + col] = (bf16_t)(o[nt][r] / lrow[r]);
        }
    }
}

// ---------------------------------------------------------------------------
// MA: causal no-softmax attention + y_sum.  ma = qa·(kc) + 0.5*R[q] with
// kc = sigmoid(k2*0.0025) - 0.5 (keeps signal above bf16 ulp at 0.5).
// ---------------------------------------------------------------------------
__global__ __launch_bounds__(256) void attn_ma_mfma(
    const bf16_t* __restrict__ qkb, const bf16_t* __restrict__ k2b,
    const bf16_t* __restrict__ xb,  const bf16_t* __restrict__ yarb,
    bf16_t* __restrict__ ysumb)
{
    const int qt = blockIdx.x, h = blockIdx.y, b = blockIdx.z;
    const int tid = threadIdx.x, wave = tid >> 6, lane = tid & 63;
    const int l15 = lane & 15, quad = lane >> 4;
    const int q0 = qt * 64;

    __shared__ __align__(16) unsigned short Qs[64 * 72];   // qa [q][d] padded
    __shared__ __align__(16) unsigned short Ks[64 * 72];   // kc [s][d] padded
    __shared__ __align__(16) unsigned short Et[64 * 72];   // E^T [d][s] padded
    __shared__ __align__(16) unsigned short Pw[4][16 * 72];
    __shared__ float Rl[64];

    // stage qa = q*0.125 * (q>0 ? 0.02 : 1)
    #pragma unroll
    for (int j = 0; j < 4; ++j) {
        const int idx = tid + 256*j;
        const int row = idx >> 4, d0 = (idx & 15) * 4;
        bf16x4 v = *(const bf16x4*)(qkb + (size_t)(b*TT + q0 + row)*(2*DDE) + h*HDD + d0);
        bf16x4 oq;
        #pragma unroll
        for (int u = 0; u < 4; ++u) {
            float q = (float)v[u];
            float z = q * 0.125f;
            oq[u] = (bf16_t)((q > 0.f) ? z * 0.02f : z);
        }
        *(bf16x4*)(Qs + row*72 + d0) = oq;
    }
    __syncthreads();
    if (tid < 64) {   // R[q] = sum_d qa[q][d] (fp32, from staged bf16 = exact match to MFMA inputs)
        float s = 0.f;
        #pragma unroll
        for (int c = 0; c < 8; ++c) {
            bf16x8 v = *(const bf16x8*)(Qs + tid*72 + c*8);
            #pragma unroll
            for (int u = 0; u < 8; ++u) s += (float)v[u];
        }
        Rl[tid] = s;
    }
    __syncthreads();
    float Rr[4];
    #pragma unroll
    for (int r = 0; r < 4; ++r) Rr[r] = Rl[16*wave + quad*4 + r];

    f32x4 o[4];
    #pragma unroll
    for (int nt = 0; nt < 4; ++nt) o[nt] = (f32x4)0.f;
    const int ql_tile = 16*wave + quad*4;

    for (int kt = 0; kt <= qt; ++kt) {
        const int s0 = kt * 64;
        __syncthreads();
        // stage kc (shifted s-1, row 0 of tile 0 zeroed)
        #pragma unroll
        for (int j = 0; j < 4; ++j) {
            const int idx = tid + 256*j;
            const int row = idx >> 4, d0 = (idx & 15) * 4;
            const int tok = s0 + row - 1;
            bf16x4 ov;
            if (tok >= 0) {
                bf16x4 v = *(const bf16x4*)(k2b + (size_t)(b*TT + tok)*DDE + h*HDD + d0);
                #pragma unroll
                for (int u = 0; u < 4; ++u) {
                    float z = (float)v[u] * 0.0025f;
                    ov[u] = (bf16_t)(1.f / (1.f + __expf(-z)) - 0.5f);
                }
            } else {
                #pragma unroll
                for (int u = 0; u < 4; ++u) ov[u] = (bf16_t)0.f;
            }
            *(bf16x4*)(Ks + row*72 + d0) = ov;
        }
        // stage E^T: e[s] = v[s] - y_ar[s-1], s>=1
        {
            const int d = tid & 63, sb0 = (tid >> 6) * 4;
            #pragma unroll
            for (int j = 0; j < 4; ++j) {
                const int sb = sb0 + j*16;
                unsigned long long w = 0;
                #pragma unroll
                for (int u = 0; u < 4; ++u) {
                    const int sg = s0 + sb + u;
                    float e = 0.f;
                    if (sg >= 1) {
                        float vx = (float)xb[(size_t)(b*TT + sg)*DDE + h*HDD + d];
                        float vy = (float)yarb[(size_t)(b*TT + sg - 1)*DDE + h*HDD + d];
                        e = vx - vy;
                    }
                    w |= (unsigned long long)bf2us((bf16_t)e) << (16*u);
                }
                *(unsigned long long*)(Et + d*72 + sb) = w;
            }
        }
        __syncthreads();

        // S = qa kc^T
        bf16x8 qa0 = *(const bf16x8*)(Qs + (16*wave + l15)*72 + quad*8);
        bf16x8 qa1 = *(const bf16x8*)(Qs + (16*wave + l15)*72 + 32 + quad*8);
        f32x4 sv[4];
        #pragma unroll
        for (int nt = 0; nt < 4; ++nt) {
            const unsigned short* kr = Ks + (nt*16 + l15)*72;
            bf16x8 kb0 = *(const bf16x8*)(kr + quad*8);
            bf16x8 kb1 = *(const bf16x8*)(kr + 32 + quad*8);
            f32x4 z = (f32x4)0.f;
            z = MFMA(qa0, kb0, z);
            z = MFMA(qa1, kb1, z);
            sv[nt] = z;
        }
        // P = S + 0.5 R[q], masked (1 <= s <= q)
        const bool diag = (kt == qt);
        unsigned short* pw = Pw[wave];
        #pragma unroll
        for (int r = 0; r < 4; ++r)
            #pragma unroll
            for (int nt = 0; nt < 4; ++nt) {
                const int sl = nt*16 + l15;
                float p = sv[nt][r] + 0.5f * Rr[r];
                if (kt == 0 && sl == 0) p = 0.f;
                if (diag && sl > ql_tile + r) p = 0.f;
                pw[(quad*4 + r)*72 + sl] = bf2us((bf16_t)p);
            }
        // O += P E
        bf16x8 pa0 = *(const bf16x8*)(pw + l15*72 + quad*8);
        bf16x8 pa1 = *(const bf16x8*)(pw + l15*72 + 32 + quad*8);
        #pragma unroll
        for (int nt = 0; nt < 4; ++nt) {
            const unsigned short* er = Et + (nt*16 + l15)*72;
            bf16x8 eb0 = *(const bf16x8*)(er + quad*8);
            bf16x8 eb1 = *(const bf16x8*)(er + 32 + quad*8);
            o[nt] = MFMA(pa0, eb0, o[nt]);
            o[nt] = MFMA(pa1, eb1, o[nt]);
        }
    }

    // y_sum = y_ar + y_ma
    #pragma unroll
    for (int nt = 0; nt < 4; ++nt) {
        const int col = h*HDD + nt*16 + l15;
        #pragma unroll
        for (int r = 0; r < 4; ++r) {
            const size_t idx = (size_t)(b*TT + q0 + 16*wave + quad*4 + r)*DDE + col;
            ysumb[idx] = (bf16_t)((float)yarb[idx] + o[nt][r]);
        }
    }
}

// ---------------------------------------------------------------------------
extern "C" void kernel_launch(void* const* d_in, const int* in_sizes, int n_in,
                              void* d_out, int out_size, void* d_ws, size_t ws_size,
                              hipStream_t stream)
{
    const float* x      = (const float*)d_in[0];
    const float* w_attn = (const float*)d_in[1];
    const float* b_attn = (const float*)d_in[2];
    const float* w_k2   = (const float*)d_in[3];
    const float* b_k2   = (const float*)d_in[4];
    const float* w_proj = (const float*)d_in[5];
    const float* b_proj = (const float*)d_in[6];

    const size_t NX  = (size_t)BB*TT*DDE;       // 4,194,304
    const size_t NWA = (size_t)2*DDE*DDE;       // 2,097,152
    const size_t NW  = (size_t)DDE*DDE;         // 1,048,576
    const size_t NQK = (size_t)BB*TT*2*DDE;     // 8,388,608

    bf16_t* xb   = (bf16_t*)d_ws;
    bf16_t* wab  = xb   + NX;
    bf16_t* wkb  = wab  + NWA;
    bf16_t* wpb  = wkb  + NW;
    bf16_t* qkb  = wpb  + NW;
    bf16_t* k2b  = qkb  + NQK;
    bf16_t* yar  = k2b  + NX;
    bf16_t* ysum = yar  + NX;

    cvt_f32_bf16<<<NX  / 1024, 256, 0, stream>>>(x,      xb,  (int)NX);
    cvt_f32_bf16<<<NWA / 1024, 256, 0, stream>>>(w_attn, wab, (int)NWA);
    cvt_f32_bf16<<<NW  / 1024, 256, 0, stream>>>(w_k2,   wkb, (int)NW);
    cvt_f32_bf16<<<NW  / 1024, 256, 0, stream>>>(w_proj, wpb, (int)NW);

    const int M = BB * TT;
    gemm_bf16<1><<<dim3(2*DDE/128, M/128), 256, 0, stream>>>(xb, wab, b_attn, qkb, M, 2*DDE, DDE, 1.f);
    gemm_bf16<1><<<dim3(DDE/128,   M/128), 256, 0, stream>>>(xb, wkb, b_k2,  k2b, M, DDE,   DDE, 1.f);

    dim3 ga(TT/64, NHH, BB);
    attn_ar_mfma<<<ga, 256, 0, stream>>>(qkb, xb, yar);
    attn_ma_mfma<<<ga, 256, 0, stream>>>(qkb, k2b, xb, yar, ysum);

    gemm_bf16<0><<<dim3(DDE/128, M/128), 256, 0, stream>>>(ysum, wpb, b_proj, d_out, M, DDE, DDE, 2.f);
}

// Round 3
// 350.058 us; speedup vs baseline: 7.1059x; 1.3846x over previous
//
#include <hip/hip_runtime.h>
#include <hip/hip_bf16.h>
#include <math.h>

#define BB  2
#define TT  2048
#define DDE 1024
#define NHH 16
#define HDD 64

typedef __bf16 bf16_t;
typedef __attribute__((ext_vector_type(8))) __bf16 bf16x8;
typedef __attribute__((ext_vector_type(4))) __bf16 bf16x4;
typedef __attribute__((ext_vector_type(4))) float  f32x4;

#define MFMA(a, b, c) __builtin_amdgcn_mfma_f32_16x16x32_bf16((a), (b), (c), 0, 0, 0)

__device__ inline unsigned short bf2us(bf16_t x) {
    union { bf16_t h; unsigned short u; } c; c.h = x; return c.u;
}

__device__ inline void gll16(const bf16_t* g, unsigned short* l) {
    __builtin_amdgcn_global_load_lds(
        (const __attribute__((address_space(1))) void*)g,
        (__attribute__((address_space(3))) void*)l, 16, 0, 0);
}

// Stage [ROWS x 64] bf16 tile (row stride gstride elems) into LDS via
// global_load_lds, chunk-swizzled: LDS elem [r][ (c ^ (r&7))*8 + j ].
template<int ROWS>
__device__ inline void stage_tile(const bf16_t* g0, size_t gstride,
                                  unsigned short* lds, int wave, int lane)
{
    const int r8 = lane >> 3;
    const int ck = (lane & 7) ^ r8;
    constexpr int RW = ROWS / 4;
    const bf16_t* g = g0 + (size_t)(wave * RW + r8) * gstride + ck * 8;
    unsigned short* l = lds + wave * RW * 64 + lane * 8;
    #pragma unroll
    for (int i = 0; i < RW / 8; ++i)
        gll16(g + (size_t)(i * 8) * gstride, l + i * 512);
}

// ---------------------------------------------------------------------------
__global__ __launch_bounds__(256) void cvt_f32_bf16(
    const float* __restrict__ in, bf16_t* __restrict__ out, int n)
{
    int i = (blockIdx.x * 256 + threadIdx.x) * 4;
    if (i < n) {
        float4 v = *(const float4*)(in + i);
        bf16x4 o;
        o[0] = (bf16_t)v.x; o[1] = (bf16_t)v.y;
        o[2] = (bf16_t)v.z; o[3] = (bf16_t)v.w;
        *(bf16x4*)(out + i) = o;
    }
}

// ---------------------------------------------------------------------------
// Per-head 64x64 transpose: dst[bh][d][t] = src[b][t][h*64+d]  (SUB: minus
// sub[b][t-1][...], zero at t==0).  Conflict-free rotation swizzle.
// ---------------------------------------------------------------------------
template<int SUB>
__global__ __launch_bounds__(256) void transpose_head(
    const bf16_t* __restrict__ src, const bf16_t* __restrict__ sub,
    bf16_t* __restrict__ dst)
{
    const int t0 = blockIdx.x * 64, h = blockIdx.y, b = blockIdx.z;
    const int tid = threadIdx.x;
    __shared__ __align__(16) bf16_t tile[64 * 64];

    #pragma unroll
    for (int it = 0; it < 2; ++it) {
        const int t = it * 32 + (tid >> 3);
        const int cw = tid & 7;
        const int slot = (cw + (t >> 3)) & 7;
        const int tg = t0 + t;
        bf16x8 v;
        if (SUB) {
            if (tg == 0) {
                #pragma unroll
                for (int u = 0; u < 8; ++u) v[u] = (bf16_t)0.f;
            } else {
                bf16x8 a = *(const bf16x8*)(src + (size_t)(b*TT + tg)*DDE + h*HDD + cw*8);
                bf16x8 c = *(const bf16x8*)(sub + (size_t)(b*TT + tg - 1)*DDE + h*HDD + cw*8);
                #pragma unroll
                for (int u = 0; u < 8; ++u) v[u] = (bf16_t)((float)a[u] - (float)c[u]);
            }
        } else {
            v = *(const bf16x8*)(src + (size_t)(b*TT + tg)*DDE + h*HDD + cw*8);
        }
        *(bf16x8*)(tile + t*64 + slot*8) = v;
    }
    __syncthreads();
    const int bh = b * NHH + h;
    #pragma unroll
    for (int it = 0; it < 2; ++it) {
        const int d = it * 32 + (tid >> 3);
        const int co = tid & 7;
        const int slot = ((d >> 3) + co) & 7;
        bf16x8 o;
        #pragma unroll
        for (int j = 0; j < 8; ++j)
            o[j] = tile[(co*8 + j)*64 + slot*8 + (d & 7)];
        *(bf16x8*)(dst + (size_t)(bh*64 + d)*TT + t0 + co*8) = o;
    }
}

// ---------------------------------------------------------------------------
// Fused QKV GEMM: A[4096x1024] x [w_attn;w_k2]^T.  Region by column tile:
//   [0,1024):  q  -> qkb raw, qab = leaky(q*0.125)
//   [1024,2048): k -> qkb raw
//   [2048,3072): k2 -> kcs[t+1] = sigmoid(k2*0.0025)-0.5 (shifted, row0=0)
// ---------------------------------------------------------------------------
__global__ __launch_bounds__(256) void gemm_qkk2(
    const bf16_t* __restrict__ A, const bf16_t* __restrict__ wab,
    const bf16_t* __restrict__ wkb, const float* __restrict__ b_attn,
    const float* __restrict__ b_k2, bf16_t* __restrict__ qkb,
    bf16_t* __restrict__ qab, bf16_t* __restrict__ kcs)
{
    __shared__ __align__(16) unsigned short As[128 * 32];
    __shared__ __align__(16) unsigned short Bs[128 * 32];
    const int tid  = threadIdx.x;
    const int wave = tid >> 6, lane = tid & 63;
    const int l15  = lane & 15, quad = lane >> 4;
    const int bm = blockIdx.y * 128, bn = blockIdx.x * 128;
    const int wm = (wave & 1) * 64, wn = (wave >> 1) * 64;
    const int region = bn >> 10;
    const int K = DDE;

    const bf16_t* W = (region < 2) ? wab + (size_t)bn * K
                                   : wkb + (size_t)(bn - 2048) * K;
    const float* bp = (region < 2) ? b_attn + bn : b_k2 + (bn - 2048);

    f32x4 acc[4][4];
    #pragma unroll
    for (int i = 0; i < 4; ++i)
        #pragma unroll
        for (int j = 0; j < 4; ++j) acc[i][j] = (f32x4)0.f;

    const int srow = wave * 32 + (lane >> 2);
    const int skof = (lane & 3) * 8;
    const bf16_t* ga = A + (size_t)(bm + srow) * K + skof;
    const bf16_t* gw = W + (size_t)srow * K + skof;
    unsigned short* la = As + wave * 1024 + lane * 8;
    unsigned short* lb = Bs + wave * 1024 + lane * 8;

    for (int k0 = 0; k0 < K; k0 += 32) {
        __syncthreads();
        gll16(ga + k0,                la);
        gll16(ga + k0 + (size_t)16*K, la + 512);
        gll16(gw + k0,                lb);
        gll16(gw + k0 + (size_t)16*K, lb + 512);
        __syncthreads();
        bf16x8 af[4], bfr[4];
        #pragma unroll
        for (int mt = 0; mt < 4; ++mt)
            af[mt] = *(const bf16x8*)(As + (wm + mt*16 + l15) * 32 + quad * 8);
        #pragma unroll
        for (int nt = 0; nt < 4; ++nt)
            bfr[nt] = *(const bf16x8*)(Bs + (wn + nt*16 + l15) * 32 + quad * 8);
        #pragma unroll
        for (int mt = 0; mt < 4; ++mt)
            #pragma unroll
            for (int nt = 0; nt < 4; ++nt)
                acc[mt][nt] = MFMA(af[mt], bfr[nt], acc[mt][nt]);
    }

    #pragma unroll
    for (int nt = 0; nt < 4; ++nt) {
        const int cl = wn + nt*16 + l15;
        const float bj = bp[cl];
        const int cg = bn + cl;
        #pragma unroll
        for (int mt = 0; mt < 4; ++mt)
            #pragma unroll
            for (int r = 0; r < 4; ++r) {
                const int row = bm + wm + mt*16 + quad*4 + r;
                const float v = acc[mt][nt][r] + bj;
                if (region == 0) {
                    qkb[(size_t)row * (2*DDE) + cg] = (bf16_t)v;
                    const float z = v * 0.125f;
                    qab[(size_t)row * DDE + cg] = (bf16_t)((v > 0.f) ? 0.02f*z : z);
                } else if (region == 1) {
                    qkb[(size_t)row * (2*DDE) + cg] = (bf16_t)v;
                } else {
                    const int c2 = cg - 2048;
                    const float kc = 1.f/(1.f + __expf(-v*0.0025f)) - 0.5f;
                    if (((row + 1) & (TT - 1)) != 0)
                        kcs[(size_t)(row + 1) * DDE + c2] = (bf16_t)kc;
                    if ((row & (TT - 1)) == 0)
                        kcs[(size_t)row * DDE + c2] = (bf16_t)0.f;
                }
            }
    }
}

// ---------------------------------------------------------------------------
// proj GEMM (fp32 out): C = A W^T + 2*bias
// ---------------------------------------------------------------------------
__global__ __launch_bounds__(256) void gemm_proj(
    const bf16_t* __restrict__ A, const bf16_t* __restrict__ W,
    const float* __restrict__ bias, float* __restrict__ C,
    int M, int N, int K, float bmul)
{
    __shared__ __align__(16) unsigned short As[128 * 32];
    __shared__ __align__(16) unsigned short Bs[128 * 32];
    const int tid  = threadIdx.x;
    const int wave = tid >> 6, lane = tid & 63;
    const int l15  = lane & 15, quad = lane >> 4;
    const int bm = blockIdx.y * 128, bn = blockIdx.x * 128;
    const int wm = (wave & 1) * 64, wn = (wave >> 1) * 64;

    f32x4 acc[4][4];
    #pragma unroll
    for (int i = 0; i < 4; ++i)
        #pragma unroll
        for (int j = 0; j < 4; ++j) acc[i][j] = (f32x4)0.f;

    const int srow = wave * 32 + (lane >> 2);
    const int skof = (lane & 3) * 8;
    const bf16_t* ga = A + (size_t)(bm + srow) * K + skof;
    const bf16_t* gw = W + (size_t)(bn + srow) * K + skof;
    unsigned short* la = As + wave * 1024 + lane * 8;
    unsigned short* lb = Bs + wave * 1024 + lane * 8;

    for (int k0 = 0; k0 < K; k0 += 32) {
        __syncthreads();
        gll16(ga + k0,                la);
        gll16(ga + k0 + (size_t)16*K, la + 512);
        gll16(gw + k0,                lb);
        gll16(gw + k0 + (size_t)16*K, lb + 512);
        __syncthreads();
        bf16x8 af[4], bfr[4];
        #pragma unroll
        for (int mt = 0; mt < 4; ++mt)
            af[mt] = *(const bf16x8*)(As + (wm + mt*16 + l15) * 32 + quad * 8);
        #pragma unroll
        for (int nt = 0; nt < 4; ++nt)
            bfr[nt] = *(const bf16x8*)(Bs + (wn + nt*16 + l15) * 32 + quad * 8);
        #pragma unroll
        for (int mt = 0; mt < 4; ++mt)
            #pragma unroll
            for (int nt = 0; nt < 4; ++nt)
                acc[mt][nt] = MFMA(af[mt], bfr[nt], acc[mt][nt]);
    }

    #pragma unroll
    for (int nt = 0; nt < 4; ++nt) {
        const int col = bn + wn + nt*16 + l15;
        const float bj = bias[col] * bmul;
        #pragma unroll
        for (int mt = 0; mt < 4; ++mt)
            #pragma unroll
            for (int r = 0; r < 4; ++r) {
                const int row = bm + wm + mt*16 + quad*4 + r;
                C[(size_t)row * N + col] = acc[mt][nt][r] + bj;
            }
    }
}

// ---------------------------------------------------------------------------
// AR: flash causal softmax attention.  Block = 128 q x (head, batch);
// wave owns 32 q rows.  All tiles staged via swizzled global_load_lds.
// ---------------------------------------------------------------------------
__global__ __launch_bounds__(256) void attn_ar_mfma(
    const bf16_t* __restrict__ qkb, const bf16_t* __restrict__ vtg,
    bf16_t* __restrict__ yarb)
{
    const int qtb = gridDim.x - 1 - blockIdx.x;   // big blocks first
    const int h = blockIdx.y, b = blockIdx.z;
    const int tid = threadIdx.x, wave = tid >> 6, lane = tid & 63;
    const int l15 = lane & 15, quad = lane >> 4;
    const int q0 = qtb * 128;
    const int bh = b * NHH + h;

    __shared__ __align__(16) unsigned short Qs[128 * 64];
    __shared__ __align__(16) unsigned short Ks[64 * 64];
    __shared__ __align__(16) unsigned short Vs[64 * 64];
    __shared__ __align__(16) unsigned short Pw[4][32 * 72];

    stage_tile<128>(qkb + (size_t)(b*TT + q0) * (2*DDE) + h*HDD, 2*DDE, Qs, wave, lane);
    __syncthreads();

    bf16x8 qf[2][2];
    #pragma unroll
    for (int mt = 0; mt < 2; ++mt)
        #pragma unroll
        for (int kc = 0; kc < 2; ++kc)
            qf[mt][kc] = *(const bf16x8*)(Qs + (wave*32 + mt*16 + l15)*64
                                          + ((kc*4 + quad) ^ (l15 & 7))*8);

    f32x4 o[2][4];
    float mrow[2][4], lrow[2][4];
    #pragma unroll
    for (int mt = 0; mt < 2; ++mt) {
        #pragma unroll
        for (int nt = 0; nt < 4; ++nt) o[mt][nt] = (f32x4)0.f;
        #pragma unroll
        for (int r = 0; r < 4; ++r) { mrow[mt][r] = -1e30f; lrow[mt][r] = 0.f; }
    }

    const int qw0 = q0 + wave * 32;
    const int nkt = 2 * qtb + 2;
    for (int kt = 0; kt < nkt; ++kt) {
        const int s0 = kt * 64;
        __syncthreads();
        stage_tile<64>(qkb + (size_t)(b*TT + s0)*(2*DDE) + DDE + h*HDD, 2*DDE, Ks, wave, lane);
        stage_tile<64>(vtg + (size_t)(bh*64)*TT + s0, TT, Vs, wave, lane);
        __syncthreads();
        if (s0 > qw0 + 31) continue;   // wave fully above diagonal

        f32x4 sv[2][4];
        #pragma unroll
        for (int nt = 0; nt < 4; ++nt) {
            const unsigned short* kr = Ks + (nt*16 + l15)*64;
            bf16x8 kb0 = *(const bf16x8*)(kr + ((quad    ) ^ (l15 & 7))*8);
            bf16x8 kb1 = *(const bf16x8*)(kr + ((quad + 4) ^ (l15 & 7))*8);
            #pragma unroll
            for (int mt = 0; mt < 2; ++mt) {
                f32x4 z = (f32x4)0.f;
                z = MFMA(qf[mt][0], kb0, z);
                z = MFMA(qf[mt][1], kb1, z);
                sv[mt][nt] = z;
            }
        }
        const bool domask = (s0 + 63 > qw0);
        #pragma unroll
        for (int mt = 0; mt < 2; ++mt)
            #pragma unroll
            for (int nt = 0; nt < 4; ++nt)
                #pragma unroll
                for (int r = 0; r < 4; ++r) {
                    float v = sv[mt][nt][r] * 0.125f;
                    if (domask) {
                        const int qg = qw0 + mt*16 + quad*4 + r;
                        const int sg = s0 + nt*16 + l15;
                        if (sg > qg) v = -1e30f;
                    }
                    sv[mt][nt][r] = v;
                }
        #pragma unroll
        for (int mt = 0; mt < 2; ++mt)
            #pragma unroll
            for (int r = 0; r < 4; ++r) {
                float mx = fmaxf(fmaxf(sv[mt][0][r], sv[mt][1][r]),
                                 fmaxf(sv[mt][2][r], sv[mt][3][r]));
                mx = fmaxf(mx, __shfl_xor(mx, 1));
                mx = fmaxf(mx, __shfl_xor(mx, 2));
                mx = fmaxf(mx, __shfl_xor(mx, 4));
                mx = fmaxf(mx, __shfl_xor(mx, 8));
                const float mnew = fmaxf(mrow[mt][r], mx);
                const float al = __expf(mrow[mt][r] - mnew);
                mrow[mt][r] = mnew;
                float sm = 0.f;
                #pragma unroll
                for (int nt = 0; nt < 4; ++nt) {
                    float p = __expf(sv[mt][nt][r] - mnew);
                    sv[mt][nt][r] = p;
                    sm += p;
                }
                sm += __shfl_xor(sm, 1);
                sm += __shfl_xor(sm, 2);
                sm += __shfl_xor(sm, 4);
                sm += __shfl_xor(sm, 8);
                lrow[mt][r] = lrow[mt][r] * al + sm;
                #pragma unroll
                for (int nt = 0; nt < 4; ++nt) o[mt][nt][r] *= al;
            }
        unsigned short* pw = Pw[wave];
        #pragma unroll
        for (int mt = 0; mt < 2; ++mt)
            #pragma unroll
            for (int r = 0; r < 4; ++r)
                #pragma unroll
                for (int nt = 0; nt < 4; ++nt)
                    pw[(mt*16 + quad*4 + r)*72 + nt*16 + l15] = bf2us((bf16_t)sv[mt][nt][r]);
        bf16x8 pa[2][2];
        #pragma unroll
        for (int mt = 0; mt < 2; ++mt)
            #pragma unroll
            for (int sc = 0; sc < 2; ++sc)
                pa[mt][sc] = *(const bf16x8*)(pw + (mt*16 + l15)*72 + sc*32 + quad*8);
        #pragma unroll
        for (int nt = 0; nt < 4; ++nt) {
            const unsigned short* vr = Vs + (nt*16 + l15)*64;
            bf16x8 vb0 = *(const bf16x8*)(vr + ((quad    ) ^ (l15 & 7))*8);
            bf16x8 vb1 = *(const bf16x8*)(vr + ((quad + 4) ^ (l15 & 7))*8);
            #pragma unroll
            for (int mt = 0; mt < 2; ++mt) {
                o[mt][nt] = MFMA(pa[mt][0], vb0, o[mt][nt]);
                o[mt][nt] = MFMA(pa[mt][1], vb1, o[mt][nt]);
            }
        }
    }

    #pragma unroll
    for (int mt = 0; mt < 2; ++mt)
        #pragma unroll
        for (int nt = 0; nt < 4; ++nt)
            #pragma unroll
            for (int r = 0; r < 4; ++r) {
                const int row = qw0 + mt*16 + quad*4 + r;
                const int col = h*HDD + nt*16 + l15;
                yarb[(size_t)(b*TT + row)*DDE + col] = (bf16_t)(o[mt][nt][r] / lrow[mt][r]);
            }
}

// ---------------------------------------------------------------------------
// MA: causal attention without softmax.  P = qa.kc + 0.5*R[q] (rank-1 sigmoid
// correction), E^T pre-staged.  y_sum = y_ar + P E.
// ---------------------------------------------------------------------------
__global__ __launch_bounds__(256) void attn_ma_mfma(
    const bf16_t* __restrict__ qab, const bf16_t* __restrict__ kcs,
    const bf16_t* __restrict__ etg, const bf16_t* __restrict__ yarb,
    bf16_t* __restrict__ ysumb)
{
    const int qtb = gridDim.x - 1 - blockIdx.x;
    const int h = blockIdx.y, b = blockIdx.z;
    const int tid = threadIdx.x, wave = tid >> 6, lane = tid & 63;
    const int l15 = lane & 15, quad = lane >> 4;
    const int q0 = qtb * 128;
    const int bh = b * NHH + h;

    __shared__ __align__(16) unsigned short Qs[128 * 64];
    __shared__ __align__(16) unsigned short Ks[64 * 64];
    __shared__ __align__(16) unsigned short Es[64 * 64];
    __shared__ __align__(16) unsigned short Pw[4][32 * 72];
    __shared__ float Rl[128];

    stage_tile<128>(qab + (size_t)(b*TT + q0)*DDE + h*HDD, DDE, Qs, wave, lane);
    __syncthreads();
    if (tid < 128) {
        float s = 0.f;
        #pragma unroll
        for (int c = 0; c < 8; ++c) {
            bf16x8 v = *(const bf16x8*)(Qs + tid*64 + c*8);
            #pragma unroll
            for (int u = 0; u < 8; ++u) s += (float)v[u];
        }
        Rl[tid] = s;
    }
    __syncthreads();

    bf16x8 qf[2][2];
    float Rr[2][4];
    #pragma unroll
    for (int mt = 0; mt < 2; ++mt) {
        #pragma unroll
        for (int kc = 0; kc < 2; ++kc)
            qf[mt][kc] = *(const bf16x8*)(Qs + (wave*32 + mt*16 + l15)*64
                                          + ((kc*4 + quad) ^ (l15 & 7))*8);
        #pragma unroll
        for (int r = 0; r < 4; ++r)
            Rr[mt][r] = 0.5f * Rl[wave*32 + mt*16 + quad*4 + r];
    }

    f32x4 o[2][4];
    #pragma unroll
    for (int mt = 0; mt < 2; ++mt)
        #pragma unroll
        for (int nt = 0; nt < 4; ++nt) o[mt][nt] = (f32x4)0.f;

    const int qw0 = q0 + wave * 32;
    const int nkt = 2 * qtb + 2;
    for (int kt = 0; kt < nkt; ++kt) {
        const int s0 = kt * 64;
        __syncthreads();
        stage_tile<64>(kcs + (size_t)(b*TT + s0)*DDE + h*HDD, DDE, Ks, wave, lane);
        stage_tile<64>(etg + (size_t)(bh*64)*TT + s0, TT, Es, wave, lane);
        __syncthreads();
        if (s0 > qw0 + 31) continue;

        f32x4 sv[2][4];
        #pragma unroll
        for (int nt = 0; nt < 4; ++nt) {
            const unsigned short* kr = Ks + (nt*16 + l15)*64;
            bf16x8 kb0 = *(const bf16x8*)(kr + ((quad    ) ^ (l15 & 7))*8);
            bf16x8 kb1 = *(const bf16x8*)(kr + ((quad + 4) ^ (l15 & 7))*8);
            #pragma unroll
            for (int mt = 0; mt < 2; ++mt) {
                f32x4 z = (f32x4)0.f;
                z = MFMA(qf[mt][0], kb0, z);
                z = MFMA(qf[mt][1], kb1, z);
                sv[mt][nt] = z;
            }
        }
        const bool domask = (s0 + 63 > qw0);
        unsigned short* pw = Pw[wave];
        #pragma unroll
        for (int mt = 0; mt < 2; ++mt)
            #pragma unroll
            for (int r = 0; r < 4; ++r)
                #pragma unroll
                for (int nt = 0; nt < 4; ++nt) {
                    float p = sv[mt][nt][r] + Rr[mt][r];
                    if (domask) {
                        const int qg = qw0 + mt*16 + quad*4 + r;
                        const int sg = s0 + nt*16 + l15;
                        if (sg > qg) p = 0.f;
                    }
                    pw[(mt*16 + quad*4 + r)*72 + nt*16 + l15] = bf2us((bf16_t)p);
                }
        bf16x8 pa[2][2];
        #pragma unroll
        for (int mt = 0; mt < 2; ++mt)
            #pragma unroll
            for (int sc = 0; sc < 2; ++sc)
                pa[mt][sc] = *(const bf16x8*)(pw + (mt*16 + l15)*72 + sc*32 + quad*8);
        #pragma unroll
        for (int nt = 0; nt < 4; ++nt) {
            const unsigned short* er = Es + (nt*16 + l15)*64;
            bf16x8 eb0 = *(const bf16x8*)(er + ((quad    ) ^ (l15 & 7))*8);
            bf16x8 eb1 = *(const bf16x8*)(er + ((quad + 4) ^ (l15 & 7))*8);
            #pragma unroll
            for (int mt = 0; mt < 2; ++mt) {
                o[mt][nt] = MFMA(pa[mt][0], eb0, o[mt][nt]);
                o[mt][nt] = MFMA(pa[mt][1], eb1, o[mt][nt]);
            }
        }
    }

    #pragma unroll
    for (int mt = 0; mt < 2; ++mt)
        #pragma unroll
        for (int nt = 0; nt < 4; ++nt)
            #pragma unroll
            for (int r = 0; r < 4; ++r) {
                const int row = qw0 + mt*16 + quad*4 + r;
                const int col = h*HDD + nt*16 + l15;
                const size_t idx = (size_t)(b*TT + row)*DDE + col;
                ysumb[idx] = (bf16_t)((float)yarb[idx] + o[mt][nt][r]);
            }
}

// ---------------------------------------------------------------------------
extern "C" void kernel_launch(void* const* d_in, const int* in_sizes, int n_in,
                              void* d_out, int out_size, void* d_ws, size_t ws_size,
                              hipStream_t stream)
{
    const float* x      = (const float*)d_in[0];
    const float* w_attn = (const float*)d_in[1];
    const float* b_attn = (const float*)d_in[2];
    const float* w_k2   = (const float*)d_in[3];
    const float* b_k2   = (const float*)d_in[4];
    const float* w_proj = (const float*)d_in[5];
    const float* b_proj = (const float*)d_in[6];

    const size_t NX  = (size_t)BB*TT*DDE;
    const size_t NWA = (size_t)2*DDE*DDE;
    const size_t NW  = (size_t)DDE*DDE;
    const size_t NQK = (size_t)BB*TT*2*DDE;

    bf16_t* xb   = (bf16_t*)d_ws;
    bf16_t* wab  = xb   + NX;
    bf16_t* wkb  = wab  + NWA;
    bf16_t* wpb  = wkb  + NW;
    bf16_t* qkb  = wpb  + NW;
    bf16_t* qab  = qkb  + NQK;
    bf16_t* kcs  = qab  + NX;
    bf16_t* yar  = kcs  + NX;
    bf16_t* ysum = yar  + NX;
    bf16_t* vtg  = ysum + NX;
    bf16_t* etg  = vtg  + NX;

    cvt_f32_bf16<<<NX  / 1024, 256, 0, stream>>>(x,      xb,  (int)NX);
    cvt_f32_bf16<<<NWA / 1024, 256, 0, stream>>>(w_attn, wab, (int)NWA);
    cvt_f32_bf16<<<NW  / 1024, 256, 0, stream>>>(w_k2,   wkb, (int)NW);
    cvt_f32_bf16<<<NW  / 1024, 256, 0, stream>>>(w_proj, wpb, (int)NW);

    transpose_head<0><<<dim3(TT/64, NHH, BB), 256, 0, stream>>>(xb, nullptr, vtg);

    const int M = BB * TT;
    gemm_qkk2<<<dim3(24, M/128), 256, 0, stream>>>(xb, wab, wkb, b_attn, b_k2,
                                                    qkb, qab, kcs);

    attn_ar_mfma<<<dim3(TT/128, NHH, BB), 256, 0, stream>>>(qkb, vtg, yar);
    transpose_head<1><<<dim3(TT/64, NHH, BB), 256, 0, stream>>>(xb, yar, etg);
    attn_ma_mfma<<<dim3(TT/128, NHH, BB), 256, 0, stream>>>(qab, kcs, etg, yar, ysum);

    gemm_proj<<<dim3(DDE/128, M/128), 256, 0, stream>>>(ysum, wpb, b_proj,
                                                        (float*)d_out, M, DDE, DDE, 2.f);
}

// Round 4
// 307.188 us; speedup vs baseline: 8.0976x; 1.1396x over previous
//
#include <hip/hip_runtime.h>
#include <hip/hip_bf16.h>
#include <math.h>

#define BB  2
#define TT  2048
#define DDE 1024
#define NHH 16
#define HDD 64

typedef __bf16 bf16_t;
typedef __attribute__((ext_vector_type(8))) __bf16 bf16x8;
typedef __attribute__((ext_vector_type(4))) __bf16 bf16x4;
typedef __attribute__((ext_vector_type(4))) float  f32x4;

#define MFMA(a, b, c) __builtin_amdgcn_mfma_f32_16x16x32_bf16((a), (b), (c), 0, 0, 0)

__device__ inline unsigned short bf2us(bf16_t x) {
    union { bf16_t h; unsigned short u; } c; c.h = x; return c.u;
}

__device__ inline void gll16(const bf16_t* g, unsigned short* l) {
    __builtin_amdgcn_global_load_lds(
        (const __attribute__((address_space(1))) void*)g,
        (__attribute__((address_space(3))) void*)l, 16, 0, 0);
}

// Stage [ROWS x 64] bf16 tile (row stride gstride elems) into LDS via
// global_load_lds, chunk-swizzled: LDS elem [r][ (c ^ (r&7))*8 + j ].
template<int ROWS>
__device__ inline void stage_tile(const bf16_t* g0, size_t gstride,
                                  unsigned short* lds, int wave, int lane)
{
    const int r8 = lane >> 3;
    const int ck = (lane & 7) ^ r8;
    constexpr int RW = ROWS / 4;
    const bf16_t* g = g0 + (size_t)(wave * RW + r8) * gstride + ck * 8;
    unsigned short* l = lds + wave * RW * 64 + lane * 8;
    #pragma unroll
    for (int i = 0; i < RW / 8; ++i)
        gll16(g + (size_t)(i * 8) * gstride, l + i * 512);
}

// split-s work decomposition: 40 blocks cover 16 q-tiles x ceil(tiles/8) chunks
__device__ inline void split_decode(int wid, int& qt, int& ch) {
    const int g = (wid >= 24) ? 3 : (wid >= 12) ? 2 : (wid >= 4) ? 1 : 0;
    const int loc = wid - 2 * g * (g + 1);
    qt = 4 * g + loc / (g + 1);
    ch = loc % (g + 1);
}

// ---------------------------------------------------------------------------
__global__ __launch_bounds__(256) void cvt_f32_bf16(
    const float* __restrict__ in, bf16_t* __restrict__ out, int n)
{
    int i = (blockIdx.x * 256 + threadIdx.x) * 4;
    if (i < n) {
        float4 v = *(const float4*)(in + i);
        bf16x4 o;
        o[0] = (bf16_t)v.x; o[1] = (bf16_t)v.y;
        o[2] = (bf16_t)v.z; o[3] = (bf16_t)v.w;
        *(bf16x4*)(out + i) = o;
    }
}

// ---------------------------------------------------------------------------
// Per-head 64x64 transpose: dst[bh][d][t] = src[b][t][h*64+d]  (SUB: minus
// sub[b][t-1][...], zero at t==0).  Conflict-free rotation swizzle.
// ---------------------------------------------------------------------------
template<int SUB>
__global__ __launch_bounds__(256) void transpose_head(
    const bf16_t* __restrict__ src, const bf16_t* __restrict__ sub,
    bf16_t* __restrict__ dst)
{
    const int t0 = blockIdx.x * 64, h = blockIdx.y, b = blockIdx.z;
    const int tid = threadIdx.x;
    __shared__ __align__(16) bf16_t tile[64 * 64];

    #pragma unroll
    for (int it = 0; it < 2; ++it) {
        const int t = it * 32 + (tid >> 3);
        const int cw = tid & 7;
        const int slot = (cw + (t >> 3)) & 7;
        const int tg = t0 + t;
        bf16x8 v;
        if (SUB) {
            if (tg == 0) {
                #pragma unroll
                for (int u = 0; u < 8; ++u) v[u] = (bf16_t)0.f;
            } else {
                bf16x8 a = *(const bf16x8*)(src + (size_t)(b*TT + tg)*DDE + h*HDD + cw*8);
                bf16x8 c = *(const bf16x8*)(sub + (size_t)(b*TT + tg - 1)*DDE + h*HDD + cw*8);
                #pragma unroll
                for (int u = 0; u < 8; ++u) v[u] = (bf16_t)((float)a[u] - (float)c[u]);
            }
        } else {
            v = *(const bf16x8*)(src + (size_t)(b*TT + tg)*DDE + h*HDD + cw*8);
        }
        *(bf16x8*)(tile + t*64 + slot*8) = v;
    }
    __syncthreads();
    const int bh = b * NHH + h;
    #pragma unroll
    for (int it = 0; it < 2; ++it) {
        const int d = it * 32 + (tid >> 3);
        const int co = tid & 7;
        const int slot = ((d >> 3) + co) & 7;
        bf16x8 o;
        #pragma unroll
        for (int j = 0; j < 8; ++j)
            o[j] = tile[(co*8 + j)*64 + slot*8 + (d & 7)];
        *(bf16x8*)(dst + (size_t)(bh*64 + d)*TT + t0 + co*8) = o;
    }
}

// ---------------------------------------------------------------------------
// Fused QKV GEMM.  Region by column tile:
//   [0,1024):  q -> qkb = q*0.125*log2(e) (exp2 domain), qab = leaky(q*0.125)
//   [1024,2048): k -> qkb raw
//   [2048,3072): k2 -> kcs[t+1] = sigmoid(k2*0.0025)-0.5 (shifted, row0=0)
// ---------------------------------------------------------------------------
__global__ __launch_bounds__(256) void gemm_qkk2(
    const bf16_t* __restrict__ A, const bf16_t* __restrict__ wab,
    const bf16_t* __restrict__ wkb, const float* __restrict__ b_attn,
    const float* __restrict__ b_k2, bf16_t* __restrict__ qkb,
    bf16_t* __restrict__ qab, bf16_t* __restrict__ kcs)
{
    __shared__ __align__(16) unsigned short As[128 * 32];
    __shared__ __align__(16) unsigned short Bs[128 * 32];
    const int tid  = threadIdx.x;
    const int wave = tid >> 6, lane = tid & 63;
    const int l15  = lane & 15, quad = lane >> 4;
    const int bm = blockIdx.y * 128, bn = blockIdx.x * 128;
    const int wm = (wave & 1) * 64, wn = (wave >> 1) * 64;
    const int region = bn >> 10;
    const int K = DDE;

    const bf16_t* W = (region < 2) ? wab + (size_t)bn * K
                                   : wkb + (size_t)(bn - 2048) * K;
    const float* bp = (region < 2) ? b_attn + bn : b_k2 + (bn - 2048);

    f32x4 acc[4][4];
    #pragma unroll
    for (int i = 0; i < 4; ++i)
        #pragma unroll
        for (int j = 0; j < 4; ++j) acc[i][j] = (f32x4)0.f;

    const int srow = wave * 32 + (lane >> 2);
    const int skof = (lane & 3) * 8;
    const bf16_t* ga = A + (size_t)(bm + srow) * K + skof;
    const bf16_t* gw = W + (size_t)srow * K + skof;
    unsigned short* la = As + wave * 1024 + lane * 8;
    unsigned short* lb = Bs + wave * 1024 + lane * 8;

    for (int k0 = 0; k0 < K; k0 += 32) {
        __syncthreads();
        gll16(ga + k0,                la);
        gll16(ga + k0 + (size_t)16*K, la + 512);
        gll16(gw + k0,                lb);
        gll16(gw + k0 + (size_t)16*K, lb + 512);
        __syncthreads();
        bf16x8 af[4], bfr[4];
        #pragma unroll
        for (int mt = 0; mt < 4; ++mt)
            af[mt] = *(const bf16x8*)(As + (wm + mt*16 + l15) * 32 + quad * 8);
        #pragma unroll
        for (int nt = 0; nt < 4; ++nt)
            bfr[nt] = *(const bf16x8*)(Bs + (wn + nt*16 + l15) * 32 + quad * 8);
        #pragma unroll
        for (int mt = 0; mt < 4; ++mt)
            #pragma unroll
            for (int nt = 0; nt < 4; ++nt)
                acc[mt][nt] = MFMA(af[mt], bfr[nt], acc[mt][nt]);
    }

    #pragma unroll
    for (int nt = 0; nt < 4; ++nt) {
        const int cl = wn + nt*16 + l15;
        const float bj = bp[cl];
        const int cg = bn + cl;
        #pragma unroll
        for (int mt = 0; mt < 4; ++mt)
            #pragma unroll
            for (int r = 0; r < 4; ++r) {
                const int row = bm + wm + mt*16 + quad*4 + r;
                const float v = acc[mt][nt][r] + bj;
                if (region == 0) {
                    // q scaled into exp2 domain: 0.125 * log2(e)
                    qkb[(size_t)row * (2*DDE) + cg] = (bf16_t)(v * 0.180336880f);
                    const float z = v * 0.125f;
                    qab[(size_t)row * DDE + cg] = (bf16_t)((v > 0.f) ? 0.02f*z : z);
                } else if (region == 1) {
                    qkb[(size_t)row * (2*DDE) + cg] = (bf16_t)v;
                } else {
                    const int c2 = cg - 2048;
                    const float kc = 1.f/(1.f + __expf(-v*0.0025f)) - 0.5f;
                    if (((row + 1) & (TT - 1)) != 0)
                        kcs[(size_t)(row + 1) * DDE + c2] = (bf16_t)kc;
                    if ((row & (TT - 1)) == 0)
                        kcs[(size_t)row * DDE + c2] = (bf16_t)0.f;
                }
            }
    }
}

// ---------------------------------------------------------------------------
// proj GEMM (fp32 out): C = A W^T + 2*bias
// ---------------------------------------------------------------------------
__global__ __launch_bounds__(256) void gemm_proj(
    const bf16_t* __restrict__ A, const bf16_t* __restrict__ W,
    const float* __restrict__ bias, float* __restrict__ C,
    int M, int N, int K, float bmul)
{
    __shared__ __align__(16) unsigned short As[128 * 32];
    __shared__ __align__(16) unsigned short Bs[128 * 32];
    const int tid  = threadIdx.x;
    const int wave = tid >> 6, lane = tid & 63;
    const int l15  = lane & 15, quad = lane >> 4;
    const int bm = blockIdx.y * 128, bn = blockIdx.x * 128;
    const int wm = (wave & 1) * 64, wn = (wave >> 1) * 64;

    f32x4 acc[4][4];
    #pragma unroll
    for (int i = 0; i < 4; ++i)
        #pragma unroll
        for (int j = 0; j < 4; ++j) acc[i][j] = (f32x4)0.f;

    const int srow = wave * 32 + (lane >> 2);
    const int skof = (lane & 3) * 8;
    const bf16_t* ga = A + (size_t)(bm + srow) * K + skof;
    const bf16_t* gw = W + (size_t)(bn + srow) * K + skof;
    unsigned short* la = As + wave * 1024 + lane * 8;
    unsigned short* lb = Bs + wave * 1024 + lane * 8;

    for (int k0 = 0; k0 < K; k0 += 32) {
        __syncthreads();
        gll16(ga + k0,                la);
        gll16(ga + k0 + (size_t)16*K, la + 512);
        gll16(gw + k0,                lb);
        gll16(gw + k0 + (size_t)16*K, lb + 512);
        __syncthreads();
        bf16x8 af[4], bfr[4];
        #pragma unroll
        for (int mt = 0; mt < 4; ++mt)
            af[mt] = *(const bf16x8*)(As + (wm + mt*16 + l15) * 32 + quad * 8);
        #pragma unroll
        for (int nt = 0; nt < 4; ++nt)
            bfr[nt] = *(const bf16x8*)(Bs + (wn + nt*16 + l15) * 32 + quad * 8);
        #pragma unroll
        for (int mt = 0; mt < 4; ++mt)
            #pragma unroll
            for (int nt = 0; nt < 4; ++nt)
                acc[mt][nt] = MFMA(af[mt], bfr[nt], acc[mt][nt]);
    }

    #pragma unroll
    for (int nt = 0; nt < 4; ++nt) {
        const int col = bn + wn + nt*16 + l15;
        const float bj = bias[col] * bmul;
        #pragma unroll
        for (int mt = 0; mt < 4; ++mt)
            #pragma unroll
            for (int r = 0; r < 4; ++r) {
                const int row = bm + wm + mt*16 + quad*4 + r;
                C[(size_t)row * N + col] = acc[mt][nt][r] + bj;
            }
    }
}

// ---------------------------------------------------------------------------
// AR: fixed-max flash attention, split-s.  Block = (q-tile 128) x (s-chunk of
// 8 k-tiles).  Partials accumulated via fp32 atomics: yo += exp2(S)V, lsum +=
// row-sum(exp2(S)).  Normalized by norm_ar.
// ---------------------------------------------------------------------------
__global__ __launch_bounds__(256) void attn_ar_mfma(
    const bf16_t* __restrict__ qkb, const bf16_t* __restrict__ vtg,
    float* __restrict__ yo, float* __restrict__ lsum)
{
    int qt, ch;
    split_decode(39 - (int)blockIdx.x, qt, ch);   // big chunks dispatch first
    const int h = blockIdx.y, b = blockIdx.z;
    const int tid = threadIdx.x, wave = tid >> 6, lane = tid & 63;
    const int l15 = lane & 15, quad = lane >> 4;
    const int q0 = qt * 128;
    const int bh = b * NHH + h;

    __shared__ __align__(16) unsigned short Qs[128 * 64];
    __shared__ __align__(16) unsigned short Ks[64 * 64];
    __shared__ __align__(16) unsigned short Vs[64 * 64];
    __shared__ __align__(16) unsigned short Pw[4][32 * 72];

    stage_tile<128>(qkb + (size_t)(b*TT + q0) * (2*DDE) + h*HDD, 2*DDE, Qs, wave, lane);
    __syncthreads();

    bf16x8 qf[2][2];
    #pragma unroll
    for (int mt = 0; mt < 2; ++mt)
        #pragma unroll
        for (int kc = 0; kc < 2; ++kc)
            qf[mt][kc] = *(const bf16x8*)(Qs + (wave*32 + mt*16 + l15)*64
                                          + ((kc*4 + quad) ^ (l15 & 7))*8);

    f32x4 o[2][4];
    float lrow[2][4];
    #pragma unroll
    for (int mt = 0; mt < 2; ++mt) {
        #pragma unroll
        for (int nt = 0; nt < 4; ++nt) o[mt][nt] = (f32x4)0.f;
        #pragma unroll
        for (int r = 0; r < 4; ++r) lrow[mt][r] = 0.f;
    }

    const int qw0 = q0 + wave * 32;
    const int kt0 = ch * 8;
    const int kt1 = min(kt0 + 8, 2*qt + 2);
    bool did = false;

    for (int kt = kt0; kt < kt1; ++kt) {
        const int s0 = kt * 64;
        __syncthreads();
        stage_tile<64>(qkb + (size_t)(b*TT + s0)*(2*DDE) + DDE + h*HDD, 2*DDE, Ks, wave, lane);
        stage_tile<64>(vtg + (size_t)(bh*64)*TT + s0, TT, Vs, wave, lane);
        __syncthreads();
        if (s0 > qw0 + 31) continue;   // wave fully above diagonal
        did = true;

        f32x4 sv[2][4];
        #pragma unroll
        for (int nt = 0; nt < 4; ++nt) {
            const unsigned short* kr = Ks + (nt*16 + l15)*64;
            bf16x8 kb0 = *(const bf16x8*)(kr + ((quad    ) ^ (l15 & 7))*8);
            bf16x8 kb1 = *(const bf16x8*)(kr + ((quad + 4) ^ (l15 & 7))*8);
            #pragma unroll
            for (int mt = 0; mt < 2; ++mt) {
                f32x4 z = (f32x4)0.f;
                z = MFMA(qf[mt][0], kb0, z);
                z = MFMA(qf[mt][1], kb1, z);
                sv[mt][nt] = z;
            }
        }
        // p = exp2(S)  (S already in exp2 domain; fixed max = 0)
        const bool domask = (s0 + 63 > qw0);
        unsigned short* pw = Pw[wave];
        #pragma unroll
        for (int mt = 0; mt < 2; ++mt)
            #pragma unroll
            for (int r = 0; r < 4; ++r)
                #pragma unroll
                for (int nt = 0; nt < 4; ++nt) {
                    float p = exp2f(sv[mt][nt][r]);
                    if (domask) {
                        const int qg = qw0 + mt*16 + quad*4 + r;
                        const int sg = s0 + nt*16 + l15;
                        if (sg > qg) p = 0.f;
                    }
                    lrow[mt][r] += p;
                    pw[(mt*16 + quad*4 + r)*72 + nt*16 + l15] = bf2us((bf16_t)p);
                }
        bf16x8 pa[2][2];
        #pragma unroll
        for (int mt = 0; mt < 2; ++mt)
            #pragma unroll
            for (int sc = 0; sc < 2; ++sc)
                pa[mt][sc] = *(const bf16x8*)(pw + (mt*16 + l15)*72 + sc*32 + quad*8);
        #pragma unroll
        for (int nt = 0; nt < 4; ++nt) {
            const unsigned short* vr = Vs + (nt*16 + l15)*64;
            bf16x8 vb0 = *(const bf16x8*)(vr + ((quad    ) ^ (l15 & 7))*8);
            bf16x8 vb1 = *(const bf16x8*)(vr + ((quad + 4) ^ (l15 & 7))*8);
            #pragma unroll
            for (int mt = 0; mt < 2; ++mt) {
                o[mt][nt] = MFMA(pa[mt][0], vb0, o[mt][nt]);
                o[mt][nt] = MFMA(pa[mt][1], vb1, o[mt][nt]);
            }
        }
    }

    if (did) {
        #pragma unroll
        for (int mt = 0; mt < 2; ++mt)
            #pragma unroll
            for (int r = 0; r < 4; ++r) {
                float lv = lrow[mt][r];
                lv += __shfl_xor(lv, 1);
                lv += __shfl_xor(lv, 2);
                lv += __shfl_xor(lv, 4);
                lv += __shfl_xor(lv, 8);
                if (l15 == 0)
                    atomicAdd(lsum + (size_t)bh*TT + qw0 + mt*16 + quad*4 + r, lv);
            }
        #pragma unroll
        for (int mt = 0; mt < 2; ++mt)
            #pragma unroll
            for (int nt = 0; nt < 4; ++nt)
                #pragma unroll
                for (int r = 0; r < 4; ++r) {
                    const int row = qw0 + mt*16 + quad*4 + r;
                    const int col = h*HDD + nt*16 + l15;
                    atomicAdd(yo + (size_t)(b*TT + row)*DDE + col, o[mt][nt][r]);
                }
    }
}

// ---------------------------------------------------------------------------
// normalize: yarb = bf16( yo / lsum[row] )
// ---------------------------------------------------------------------------
__global__ __launch_bounds__(256) void norm_ar(
    const float* __restrict__ yo, const float* __restrict__ ls,
    bf16_t* __restrict__ yarb)
{
    const size_t e = ((size_t)blockIdx.x * 256 + threadIdx.x) * 4;
    float4 v = *(const float4*)(yo + e);
    const size_t tg = e >> 10;          // b*TT + t   (DDE=1024)
    const int c = (int)(e & (DDE - 1));
    const int h = c >> 6;
    const size_t bq = tg >> 11, t = tg & (TT - 1);
    const float inv = 1.f / ls[(bq*NHH + h)*TT + t];
    bf16x4 o;
    o[0] = (bf16_t)(v.x * inv); o[1] = (bf16_t)(v.y * inv);
    o[2] = (bf16_t)(v.z * inv); o[3] = (bf16_t)(v.w * inv);
    *(bf16x4*)(yarb + e) = o;
}

// ---------------------------------------------------------------------------
// MA: linear causal attention, split-s.  P = qa.kc + 0.5*R[q] masked to
// [1, q]; partial P.E accumulated into ma (fp32 atomics).
// ---------------------------------------------------------------------------
__global__ __launch_bounds__(256) void attn_ma_mfma(
    const bf16_t* __restrict__ qab, const bf16_t* __restrict__ kcs,
    const bf16_t* __restrict__ etg, float* __restrict__ ma)
{
    int qt, ch;
    split_decode(39 - (int)blockIdx.x, qt, ch);
    const int h = blockIdx.y, b = blockIdx.z;
    const int tid = threadIdx.x, wave = tid >> 6, lane = tid & 63;
    const int l15 = lane & 15, quad = lane >> 4;
    const int q0 = qt * 128;
    const int bh = b * NHH + h;

    __shared__ __align__(16) unsigned short Qs[128 * 64];
    __shared__ __align__(16) unsigned short Ks[64 * 64];
    __shared__ __align__(16) unsigned short Es[64 * 64];
    __shared__ __align__(16) unsigned short Pw[4][32 * 72];
    __shared__ float Rl[128];

    stage_tile<128>(qab + (size_t)(b*TT + q0)*DDE + h*HDD, DDE, Qs, wave, lane);
    __syncthreads();
    if (tid < 128) {   // row sums of qa (swizzle is a row permutation: sum ok)
        float s = 0.f;
        #pragma unroll
        for (int c = 0; c < 8; ++c) {
            bf16x8 v = *(const bf16x8*)(Qs + tid*64 + c*8);
            #pragma unroll
            for (int u = 0; u < 8; ++u) s += (float)v[u];
        }
        Rl[tid] = s;
    }
    __syncthreads();

    bf16x8 qf[2][2];
    float Rr[2][4];
    #pragma unroll
    for (int mt = 0; mt < 2; ++mt) {
        #pragma unroll
        for (int kc = 0; kc < 2; ++kc)
            qf[mt][kc] = *(const bf16x8*)(Qs + (wave*32 + mt*16 + l15)*64
                                          + ((kc*4 + quad) ^ (l15 & 7))*8);
        #pragma unroll
        for (int r = 0; r < 4; ++r)
            Rr[mt][r] = 0.5f * Rl[wave*32 + mt*16 + quad*4 + r];
    }

    f32x4 o[2][4];
    #pragma unroll
    for (int mt = 0; mt < 2; ++mt)
        #pragma unroll
        for (int nt = 0; nt < 4; ++nt) o[mt][nt] = (f32x4)0.f;

    const int qw0 = q0 + wave * 32;
    const int kt0 = ch * 8;
    const int kt1 = min(kt0 + 8, 2*qt + 2);
    bool did = false;

    for (int kt = kt0; kt < kt1; ++kt) {
        const int s0 = kt * 64;
        __syncthreads();
        stage_tile<64>(kcs + (size_t)(b*TT + s0)*DDE + h*HDD, DDE, Ks, wave, lane);
        stage_tile<64>(etg + (size_t)(bh*64)*TT + s0, TT, Es, wave, lane);
        __syncthreads();
        if (s0 > qw0 + 31) continue;
        did = true;

        f32x4 sv[2][4];
        #pragma unroll
        for (int nt = 0; nt < 4; ++nt) {
            const unsigned short* kr = Ks + (nt*16 + l15)*64;
            bf16x8 kb0 = *(const bf16x8*)(kr + ((quad    ) ^ (l15 & 7))*8);
            bf16x8 kb1 = *(const bf16x8*)(kr + ((quad + 4) ^ (l15 & 7))*8);
            #pragma unroll
            for (int mt = 0; mt < 2; ++mt) {
                f32x4 z = (f32x4)0.f;
                z = MFMA(qf[mt][0], kb0, z);
                z = MFMA(qf[mt][1], kb1, z);
                sv[mt][nt] = z;
            }
        }
        const bool domask = (s0 + 63 > qw0);
        const bool m0 = (kt == 0);
        unsigned short* pw = Pw[wave];
        #pragma unroll
        for (int mt = 0; mt < 2; ++mt)
            #pragma unroll
            for (int r = 0; r < 4; ++r)
                #pragma unroll
                for (int nt = 0; nt < 4; ++nt) {
                    const int sg = s0 + nt*16 + l15;
                    float p = sv[mt][nt][r] + Rr[mt][r];
                    if (m0 && sg == 0) p = 0.f;
                    if (domask) {
                        const int qg = qw0 + mt*16 + quad*4 + r;
                        if (sg > qg) p = 0.f;
                    }
                    pw[(mt*16 + quad*4 + r)*72 + nt*16 + l15] = bf2us((bf16_t)p);
                }
        bf16x8 pa[2][2];
        #pragma unroll
        for (int mt = 0; mt < 2; ++mt)
            #pragma unroll
            for (int sc = 0; sc < 2; ++sc)
                pa[mt][sc] = *(const bf16x8*)(pw + (mt*16 + l15)*72 + sc*32 + quad*8);
        #pragma unroll
        for (int nt = 0; nt < 4; ++nt) {
            const unsigned short* er = Es + (nt*16 + l15)*64;
            bf16x8 eb0 = *(const bf16x8*)(er + ((quad    ) ^ (l15 & 7))*8);
            bf16x8 eb1 = *(const bf16x8*)(er + ((quad + 4) ^ (l15 & 7))*8);
            #pragma unroll
            for (int mt = 0; mt < 2; ++mt) {
                o[mt][nt] = MFMA(pa[mt][0], eb0, o[mt][nt]);
                o[mt][nt] = MFMA(pa[mt][1], eb1, o[mt][nt]);
            }
        }
    }

    if (did) {
        #pragma unroll
        for (int mt = 0; mt < 2; ++mt)
            #pragma unroll
            for (int nt = 0; nt < 4; ++nt)
                #pragma unroll
                for (int r = 0; r < 4; ++r) {
                    const int row = qw0 + mt*16 + quad*4 + r;
                    const int col = h*HDD + nt*16 + l15;
                    atomicAdd(ma + (size_t)(b*TT + row)*DDE + col, o[mt][nt][r]);
                }
    }
}

// ---------------------------------------------------------------------------
// ysumb = bf16( yarb + ma )
// ---------------------------------------------------------------------------
__global__ __launch_bounds__(256) void combine(
    const bf16_t* __restrict__ yarb, const float* __restrict__ ma,
    bf16_t* __restrict__ ysumb)
{
    const size_t e = ((size_t)blockIdx.x * 256 + threadIdx.x) * 4;
    bf16x4 a = *(const bf16x4*)(yarb + e);
    float4 m = *(const float4*)(ma + e);
    bf16x4 o;
    o[0] = (bf16_t)((float)a[0] + m.x);
    o[1] = (bf16_t)((float)a[1] + m.y);
    o[2] = (bf16_t)((float)a[2] + m.z);
    o[3] = (bf16_t)((float)a[3] + m.w);
    *(bf16x4*)(ysumb + e) = o;
}

// ---------------------------------------------------------------------------
extern "C" void kernel_launch(void* const* d_in, const int* in_sizes, int n_in,
                              void* d_out, int out_size, void* d_ws, size_t ws_size,
                              hipStream_t stream)
{
    const float* x      = (const float*)d_in[0];
    const float* w_attn = (const float*)d_in[1];
    const float* b_attn = (const float*)d_in[2];
    const float* w_k2   = (const float*)d_in[3];
    const float* b_k2   = (const float*)d_in[4];
    const float* w_proj = (const float*)d_in[5];
    const float* b_proj = (const float*)d_in[6];

    const size_t NX  = (size_t)BB*TT*DDE;
    const size_t NWA = (size_t)2*DDE*DDE;
    const size_t NW  = (size_t)DDE*DDE;
    const size_t NQK = (size_t)BB*TT*2*DDE;

    bf16_t* xb   = (bf16_t*)d_ws;
    bf16_t* wab  = xb   + NX;
    bf16_t* wkb  = wab  + NWA;
    bf16_t* wpb  = wkb  + NW;
    bf16_t* qkb  = wpb  + NW;      // 16.8 MB; aliased by ma (f32) after attn_ar
    bf16_t* qab  = qkb  + NQK;
    bf16_t* kcs  = qab  + NX;
    bf16_t* vtg  = kcs  + NX;      // aliased by etg after attn_ar
    float*  yo   = (float*)(vtg + NX);  // 16.8 MB; aliased by ysumb after norm
    bf16_t* yarb = (bf16_t*)(yo + NX);
    float*  lsum = (float*)wab;    // aliases wab after gemm_qkk2
    float*  maf  = (float*)qkb;
    bf16_t* etg  = vtg;
    bf16_t* ysumb= (bf16_t*)yo;

    hipMemsetAsync(yo, 0, NX * sizeof(float), stream);

    cvt_f32_bf16<<<NX  / 1024, 256, 0, stream>>>(x,      xb,  (int)NX);
    cvt_f32_bf16<<<NWA / 1024, 256, 0, stream>>>(w_attn, wab, (int)NWA);
    cvt_f32_bf16<<<NW  / 1024, 256, 0, stream>>>(w_k2,   wkb, (int)NW);
    cvt_f32_bf16<<<NW  / 1024, 256, 0, stream>>>(w_proj, wpb, (int)NW);

    transpose_head<0><<<dim3(TT/64, NHH, BB), 256, 0, stream>>>(xb, nullptr, vtg);

    const int M = BB * TT;
    gemm_qkk2<<<dim3(24, M/128), 256, 0, stream>>>(xb, wab, wkb, b_attn, b_k2,
                                                    qkb, qab, kcs);
    hipMemsetAsync(lsum, 0, (size_t)BB*NHH*TT * sizeof(float), stream);

    attn_ar_mfma<<<dim3(40, NHH, BB), 256, 0, stream>>>(qkb, vtg, yo, lsum);
    norm_ar<<<NX / 1024, 256, 0, stream>>>(yo, lsum, yarb);

    hipMemsetAsync(maf, 0, NX * sizeof(float), stream);
    transpose_head<1><<<dim3(TT/64, NHH, BB), 256, 0, stream>>>(xb, yarb, etg);
    attn_ma_mfma<<<dim3(40, NHH, BB), 256, 0, stream>>>(qab, kcs, etg, maf);

    combine<<<NX / 1024, 256, 0, stream>>>(yarb, maf, ysumb);
    gemm_proj<<<dim3(DDE/128, M/128), 256, 0, stream>>>(ysumb, wpb, b_proj,
                                                        (float*)d_out, M, DDE, DDE, 2.f);
}

// Round 5
// 301.080 us; speedup vs baseline: 8.2619x; 1.0203x over previous
//
#include <hip/hip_runtime.h>
#include <hip/hip_bf16.h>
#include <math.h>

#define BB  2
#define TT  2048
#define DDE 1024
#define NHH 16
#define HDD 64

typedef __bf16 bf16_t;
typedef __attribute__((ext_vector_type(8))) __bf16 bf16x8;
typedef __attribute__((ext_vector_type(4))) __bf16 bf16x4;
typedef __attribute__((ext_vector_type(4))) float  f32x4;

#define MFMA(a, b, c) __builtin_amdgcn_mfma_f32_16x16x32_bf16((a), (b), (c), 0, 0, 0)

__device__ inline unsigned short bf2us(bf16_t x) {
    union { bf16_t h; unsigned short u; } c; c.h = x; return c.u;
}

__device__ inline void gll16(const bf16_t* g, unsigned short* l) {
    __builtin_amdgcn_global_load_lds(
        (const __attribute__((address_space(1))) void*)g,
        (__attribute__((address_space(3))) void*)l, 16, 0, 0);
}

// Stage [ROWS x 64] bf16 tile (row stride gstride elems) into LDS via
// global_load_lds, chunk-swizzled: LDS elem [r][ (c ^ (r&7))*8 + j ].
template<int ROWS>
__device__ inline void stage_tile(const bf16_t* g0, size_t gstride,
                                  unsigned short* lds, int wave, int lane)
{
    const int r8 = lane >> 3;
    const int ck = (lane & 7) ^ r8;
    constexpr int RW = ROWS / 4;
    const bf16_t* g = g0 + (size_t)(wave * RW + r8) * gstride + ck * 8;
    unsigned short* l = lds + wave * RW * 64 + lane * 8;
    #pragma unroll
    for (int i = 0; i < RW / 8; ++i)
        gll16(g + (size_t)(i * 8) * gstride, l + i * 512);
}

// split-s work decomposition: 40 blocks cover 16 q-tiles x ceil(tiles/8) chunks
__device__ inline void split_decode(int wid, int& qt, int& ch) {
    const int g = (wid >= 24) ? 3 : (wid >= 12) ? 2 : (wid >= 4) ? 1 : 0;
    const int loc = wid - 2 * g * (g + 1);
    qt = 4 * g + loc / (g + 1);
    ch = loc % (g + 1);
}

// ---------------------------------------------------------------------------
// fused fp32->bf16 conversion of x, w_attn, w_k2, w_proj into the contiguous
// ws region starting at xb.  Segment boundaries are multiples of 1024 elems.
// ---------------------------------------------------------------------------
__global__ __launch_bounds__(256) void cvt_all(
    const float* __restrict__ x, const float* __restrict__ wa,
    const float* __restrict__ wk, const float* __restrict__ wp,
    bf16_t* __restrict__ out)
{
    const size_t NX  = (size_t)BB*TT*DDE;
    const size_t NWA = (size_t)2*DDE*DDE;
    const size_t NW  = (size_t)DDE*DDE;
    const size_t e = ((size_t)blockIdx.x * 256 + threadIdx.x) * 4;
    const float* src;
    if (e < NX)                 src = x  + e;
    else if (e < NX + NWA)      src = wa + (e - NX);
    else if (e < NX + NWA + NW) src = wk + (e - NX - NWA);
    else                        src = wp + (e - NX - NWA - NW);
    float4 v = *(const float4*)src;
    bf16x4 o;
    o[0] = (bf16_t)v.x; o[1] = (bf16_t)v.y;
    o[2] = (bf16_t)v.z; o[3] = (bf16_t)v.w;
    *(bf16x4*)(out + e) = o;
}

// ---------------------------------------------------------------------------
// Per-head 64x64 transpose: dst[bh][d][t] = src[b][t][h*64+d].
// ---------------------------------------------------------------------------
__global__ __launch_bounds__(256) void transpose_head(
    const bf16_t* __restrict__ src, bf16_t* __restrict__ dst)
{
    const int t0 = blockIdx.x * 64, h = blockIdx.y, b = blockIdx.z;
    const int tid = threadIdx.x;
    __shared__ __align__(16) bf16_t tile[64 * 64];

    #pragma unroll
    for (int it = 0; it < 2; ++it) {
        const int t = it * 32 + (tid >> 3);
        const int cw = tid & 7;
        const int slot = (cw + (t >> 3)) & 7;
        bf16x8 v = *(const bf16x8*)(src + (size_t)(b*TT + t0 + t)*DDE + h*HDD + cw*8);
        *(bf16x8*)(tile + t*64 + slot*8) = v;
    }
    __syncthreads();
    const int bh = b * NHH + h;
    #pragma unroll
    for (int it = 0; it < 2; ++it) {
        const int d = it * 32 + (tid >> 3);
        const int co = tid & 7;
        const int slot = ((d >> 3) + co) & 7;
        bf16x8 o;
        #pragma unroll
        for (int j = 0; j < 8; ++j)
            o[j] = tile[(co*8 + j)*64 + slot*8 + (d & 7)];
        *(bf16x8*)(dst + (size_t)(bh*64 + d)*TT + t0 + co*8) = o;
    }
}

// ---------------------------------------------------------------------------
// Fused normalize + E-transpose:
//   n[t] = yo[t] / lsum[t]  (AR output);  yarb[t] = bf16(n[t])
//   etg[bh][d][t] = x[t][d] - n[t-1][d]  (0 at t==0)
// Row t0-1 normalization recomputed locally (no cross-block dependency).
// ---------------------------------------------------------------------------
__global__ __launch_bounds__(256) void norm_build_etg(
    const float* __restrict__ yo, const float* __restrict__ ls,
    const bf16_t* __restrict__ xb, bf16_t* __restrict__ yarb,
    bf16_t* __restrict__ etg)
{
    const int t0 = blockIdx.x * 64, h = blockIdx.y, b = blockIdx.z;
    const int tid = threadIdx.x;
    const int bh = b * NHH + h;
    __shared__ __align__(16) bf16_t tile[64 * 64];

    #pragma unroll
    for (int it = 0; it < 2; ++it) {
        const int t = it * 32 + (tid >> 3);
        const int cw = tid & 7;
        const int slot = (cw + (t >> 3)) & 7;
        const int tg = t0 + t;
        // n[tg] -> yarb
        const float inv = 1.f / ls[(size_t)bh*TT + tg];
        const float* yp = yo + (size_t)(b*TT + tg)*DDE + h*HDD + cw*8;
        float4 y0 = *(const float4*)yp;
        float4 y1 = *(const float4*)(yp + 4);
        bf16x8 nb;
        nb[0] = (bf16_t)(y0.x*inv); nb[1] = (bf16_t)(y0.y*inv);
        nb[2] = (bf16_t)(y0.z*inv); nb[3] = (bf16_t)(y0.w*inv);
        nb[4] = (bf16_t)(y1.x*inv); nb[5] = (bf16_t)(y1.y*inv);
        nb[6] = (bf16_t)(y1.z*inv); nb[7] = (bf16_t)(y1.w*inv);
        *(bf16x8*)(yarb + (size_t)(b*TT + tg)*DDE + h*HDD + cw*8) = nb;
        // e[tg] = x[tg] - n[tg-1]
        bf16x8 ev;
        if (tg == 0) {
            #pragma unroll
            for (int u = 0; u < 8; ++u) ev[u] = (bf16_t)0.f;
        } else {
            const float invp = 1.f / ls[(size_t)bh*TT + tg - 1];
            const float* ypp = yo + (size_t)(b*TT + tg - 1)*DDE + h*HDD + cw*8;
            float4 p0 = *(const float4*)ypp;
            float4 p1 = *(const float4*)(ypp + 4);
            bf16x8 xv = *(const bf16x8*)(xb + (size_t)(b*TT + tg)*DDE + h*HDD + cw*8);
            ev[0] = (bf16_t)((float)xv[0] - p0.x*invp);
            ev[1] = (bf16_t)((float)xv[1] - p0.y*invp);
            ev[2] = (bf16_t)((float)xv[2] - p0.z*invp);
            ev[3] = (bf16_t)((float)xv[3] - p0.w*invp);
            ev[4] = (bf16_t)((float)xv[4] - p1.x*invp);
            ev[5] = (bf16_t)((float)xv[5] - p1.y*invp);
            ev[6] = (bf16_t)((float)xv[6] - p1.z*invp);
            ev[7] = (bf16_t)((float)xv[7] - p1.w*invp);
        }
        *(bf16x8*)(tile + t*64 + slot*8) = ev;
    }
    __syncthreads();
    #pragma unroll
    for (int it = 0; it < 2; ++it) {
        const int d = it * 32 + (tid >> 3);
        const int co = tid & 7;
        const int slot = ((d >> 3) + co) & 7;
        bf16x8 o;
        #pragma unroll
        for (int j = 0; j < 8; ++j)
            o[j] = tile[(co*8 + j)*64 + slot*8 + (d & 7)];
        *(bf16x8*)(etg + (size_t)(bh*64 + d)*TT + t0 + co*8) = o;
    }
}

// ---------------------------------------------------------------------------
// Fused QKV GEMM, BK=64 swizzled staging.  Region by column tile:
//   [0,1024):  q -> qkb = q*0.125*log2(e) (exp2 domain), qab = leaky(q*0.125)
//   [1024,2048): k -> qkb raw
//   [2048,3072): k2 -> kcs[t+1] = sigmoid(k2*0.0025)-0.5 (shifted, row0=0)
// ---------------------------------------------------------------------------
__global__ __launch_bounds__(256) void gemm_qkk2(
    const bf16_t* __restrict__ A, const bf16_t* __restrict__ wab,
    const bf16_t* __restrict__ wkb, const float* __restrict__ b_attn,
    const float* __restrict__ b_k2, bf16_t* __restrict__ qkb,
    bf16_t* __restrict__ qab, bf16_t* __restrict__ kcs)
{
    __shared__ __align__(16) unsigned short As[128 * 64];
    __shared__ __align__(16) unsigned short Bs[128 * 64];
    const int tid  = threadIdx.x;
    const int wave = tid >> 6, lane = tid & 63;
    const int l15  = lane & 15, quad = lane >> 4;
    const int bm = blockIdx.y * 128, bn = blockIdx.x * 128;
    const int wm = (wave & 1) * 64, wn = (wave >> 1) * 64;
    const int region = bn >> 10;
    const int K = DDE;

    const bf16_t* W = (region < 2) ? wab + (size_t)bn * K
                                   : wkb + (size_t)(bn - 2048) * K;
    const float* bp = (region < 2) ? b_attn + bn : b_k2 + (bn - 2048);
    const bf16_t* Ab = A + (size_t)bm * K;

    f32x4 acc[4][4];
    #pragma unroll
    for (int i = 0; i < 4; ++i)
        #pragma unroll
        for (int j = 0; j < 4; ++j) acc[i][j] = (f32x4)0.f;

    for (int k0 = 0; k0 < K; k0 += 64) {
        __syncthreads();
        stage_tile<128>(Ab + k0, K, As, wave, lane);
        stage_tile<128>(W  + k0, K, Bs, wave, lane);
        __syncthreads();
        bf16x8 af[4][2], bfr[4][2];
        #pragma unroll
        for (int mt = 0; mt < 4; ++mt)
            #pragma unroll
            for (int kh = 0; kh < 2; ++kh)
                af[mt][kh] = *(const bf16x8*)(As + (wm + mt*16 + l15)*64
                                              + (((kh*4 + quad) ^ (l15 & 7))*8));
        #pragma unroll
        for (int nt = 0; nt < 4; ++nt)
            #pragma unroll
            for (int kh = 0; kh < 2; ++kh)
                bfr[nt][kh] = *(const bf16x8*)(Bs + (wn + nt*16 + l15)*64
                                               + (((kh*4 + quad) ^ (l15 & 7))*8));
        #pragma unroll
        for (int mt = 0; mt < 4; ++mt)
            #pragma unroll
            for (int nt = 0; nt < 4; ++nt) {
                acc[mt][nt] = MFMA(af[mt][0], bfr[nt][0], acc[mt][nt]);
                acc[mt][nt] = MFMA(af[mt][1], bfr[nt][1], acc[mt][nt]);
            }
    }

    #pragma unroll
    for (int nt = 0; nt < 4; ++nt) {
        const int cl = wn + nt*16 + l15;
        const float bj = bp[cl];
        const int cg = bn + cl;
        #pragma unroll
        for (int mt = 0; mt < 4; ++mt)
            #pragma unroll
            for (int r = 0; r < 4; ++r) {
                const int row = bm + wm + mt*16 + quad*4 + r;
                const float v = acc[mt][nt][r] + bj;
                if (region == 0) {
                    qkb[(size_t)row * (2*DDE) + cg] = (bf16_t)(v * 0.180336880f);
                    const float z = v * 0.125f;
                    qab[(size_t)row * DDE + cg] = (bf16_t)((v > 0.f) ? 0.02f*z : z);
                } else if (region == 1) {
                    qkb[(size_t)row * (2*DDE) + cg] = (bf16_t)v;
                } else {
                    const int c2 = cg - 2048;
                    const float kc = 1.f/(1.f + __expf(-v*0.0025f)) - 0.5f;
                    if (((row + 1) & (TT - 1)) != 0)
                        kcs[(size_t)(row + 1) * DDE + c2] = (bf16_t)kc;
                    if ((row & (TT - 1)) == 0)
                        kcs[(size_t)row * DDE + c2] = (bf16_t)0.f;
                }
            }
    }
}

// ---------------------------------------------------------------------------
// proj GEMM, BK=64 (fp32 out): C = A W^T + 2*bias
// ---------------------------------------------------------------------------
__global__ __launch_bounds__(256) void gemm_proj(
    const bf16_t* __restrict__ A, const bf16_t* __restrict__ W,
    const float* __restrict__ bias, float* __restrict__ C,
    int M, int N, int K, float bmul)
{
    __shared__ __align__(16) unsigned short As[128 * 64];
    __shared__ __align__(16) unsigned short Bs[128 * 64];
    const int tid  = threadIdx.x;
    const int wave = tid >> 6, lane = tid & 63;
    const int l15  = lane & 15, quad = lane >> 4;
    const int bm = blockIdx.y * 128, bn = blockIdx.x * 128;
    const int wm = (wave & 1) * 64, wn = (wave >> 1) * 64;

    const bf16_t* Ab = A + (size_t)bm * K;
    const bf16_t* Wb = W + (size_t)bn * K;

    f32x4 acc[4][4];
    #pragma unroll
    for (int i = 0; i < 4; ++i)
        #pragma unroll
        for (int j = 0; j < 4; ++j) acc[i][j] = (f32x4)0.f;

    for (int k0 = 0; k0 < K; k0 += 64) {
        __syncthreads();
        stage_tile<128>(Ab + k0, K, As, wave, lane);
        stage_tile<128>(Wb + k0, K, Bs, wave, lane);
        __syncthreads();
        bf16x8 af[4][2], bfr[4][2];
        #pragma unroll
        for (int mt = 0; mt < 4; ++mt)
            #pragma unroll
            for (int kh = 0; kh < 2; ++kh)
                af[mt][kh] = *(const bf16x8*)(As + (wm + mt*16 + l15)*64
                                              + (((kh*4 + quad) ^ (l15 & 7))*8));
        #pragma unroll
        for (int nt = 0; nt < 4; ++nt)
            #pragma unroll
            for (int kh = 0; kh < 2; ++kh)
                bfr[nt][kh] = *(const bf16x8*)(Bs + (wn + nt*16 + l15)*64
                                               + (((kh*4 + quad) ^ (l15 & 7))*8));
        #pragma unroll
        for (int mt = 0; mt < 4; ++mt)
            #pragma unroll
            for (int nt = 0; nt < 4; ++nt) {
                acc[mt][nt] = MFMA(af[mt][0], bfr[nt][0], acc[mt][nt]);
                acc[mt][nt] = MFMA(af[mt][1], bfr[nt][1], acc[mt][nt]);
            }
    }

    #pragma unroll
    for (int nt = 0; nt < 4; ++nt) {
        const int col = bn + wn + nt*16 + l15;
        const float bj = bias[col] * bmul;
        #pragma unroll
        for (int mt = 0; mt < 4; ++mt)
            #pragma unroll
            for (int r = 0; r < 4; ++r) {
                const int row = bm + wm + mt*16 + quad*4 + r;
                C[(size_t)row * N + col] = acc[mt][nt][r] + bj;
            }
    }
}

// ---------------------------------------------------------------------------
// AR: fixed-max flash attention, split-s.  Partials via fp32 atomics.
// ---------------------------------------------------------------------------
__global__ __launch_bounds__(256) void attn_ar_mfma(
    const bf16_t* __restrict__ qkb, const bf16_t* __restrict__ vtg,
    float* __restrict__ yo, float* __restrict__ lsum)
{
    int qt, ch;
    split_decode(39 - (int)blockIdx.x, qt, ch);
    const int h = blockIdx.y, b = blockIdx.z;
    const int tid = threadIdx.x, wave = tid >> 6, lane = tid & 63;
    const int l15 = lane & 15, quad = lane >> 4;
    const int q0 = qt * 128;
    const int bh = b * NHH + h;

    __shared__ __align__(16) unsigned short Qs[128 * 64];
    __shared__ __align__(16) unsigned short Ks[64 * 64];
    __shared__ __align__(16) unsigned short Vs[64 * 64];
    __shared__ __align__(16) unsigned short Pw[4][32 * 72];

    stage_tile<128>(qkb + (size_t)(b*TT + q0) * (2*DDE) + h*HDD, 2*DDE, Qs, wave, lane);
    __syncthreads();

    bf16x8 qf[2][2];
    #pragma unroll
    for (int mt = 0; mt < 2; ++mt)
        #pragma unroll
        for (int kc = 0; kc < 2; ++kc)
            qf[mt][kc] = *(const bf16x8*)(Qs + (wave*32 + mt*16 + l15)*64
                                          + ((kc*4 + quad) ^ (l15 & 7))*8);

    f32x4 o[2][4];
    float lrow[2][4];
    #pragma unroll
    for (int mt = 0; mt < 2; ++mt) {
        #pragma unroll
        for (int nt = 0; nt < 4; ++nt) o[mt][nt] = (f32x4)0.f;
        #pragma unroll
        for (int r = 0; r < 4; ++r) lrow[mt][r] = 0.f;
    }

    const int qw0 = q0 + wave * 32;
    const int kt0 = ch * 8;
    const int kt1 = min(kt0 + 8, 2*qt + 2);
    bool did = false;

    for (int kt = kt0; kt < kt1; ++kt) {
        const int s0 = kt * 64;
        __syncthreads();
        stage_tile<64>(qkb + (size_t)(b*TT + s0)*(2*DDE) + DDE + h*HDD, 2*DDE, Ks, wave, lane);
        stage_tile<64>(vtg + (size_t)(bh*64)*TT + s0, TT, Vs, wave, lane);
        __syncthreads();
        if (s0 > qw0 + 31) continue;
        did = true;

        f32x4 sv[2][4];
        #pragma unroll
        for (int nt = 0; nt < 4; ++nt) {
            const unsigned short* kr = Ks + (nt*16 + l15)*64;
            bf16x8 kb0 = *(const bf16x8*)(kr + ((quad    ) ^ (l15 & 7))*8);
            bf16x8 kb1 = *(const bf16x8*)(kr + ((quad + 4) ^ (l15 & 7))*8);
            #pragma unroll
            for (int mt = 0; mt < 2; ++mt) {
                f32x4 z = (f32x4)0.f;
                z = MFMA(qf[mt][0], kb0, z);
                z = MFMA(qf[mt][1], kb1, z);
                sv[mt][nt] = z;
            }
        }
        const bool domask = (s0 + 63 > qw0);
        unsigned short* pw = Pw[wave];
        #pragma unroll
        for (int mt = 0; mt < 2; ++mt)
            #pragma unroll
            for (int r = 0; r < 4; ++r)
                #pragma unroll
                for (int nt = 0; nt < 4; ++nt) {
                    float p = exp2f(sv[mt][nt][r]);
                    if (domask) {
                        const int qg = qw0 + mt*16 + quad*4 + r;
                        const int sg = s0 + nt*16 + l15;
                        if (sg > qg) p = 0.f;
                    }
                    lrow[mt][r] += p;
                    pw[(mt*16 + quad*4 + r)*72 + nt*16 + l15] = bf2us((bf16_t)p);
                }
        bf16x8 pa[2][2];
        #pragma unroll
        for (int mt = 0; mt < 2; ++mt)
            #pragma unroll
            for (int sc = 0; sc < 2; ++sc)
                pa[mt][sc] = *(const bf16x8*)(pw + (mt*16 + l15)*72 + sc*32 + quad*8);
        #pragma unroll
        for (int nt = 0; nt < 4; ++nt) {
            const unsigned short* vr = Vs + (nt*16 + l15)*64;
            bf16x8 vb0 = *(const bf16x8*)(vr + ((quad    ) ^ (l15 & 7))*8);
            bf16x8 vb1 = *(const bf16x8*)(vr + ((quad + 4) ^ (l15 & 7))*8);
            #pragma unroll
            for (int mt = 0; mt < 2; ++mt) {
                o[mt][nt] = MFMA(pa[mt][0], vb0, o[mt][nt]);
                o[mt][nt] = MFMA(pa[mt][1], vb1, o[mt][nt]);
            }
        }
    }

    if (did) {
        #pragma unroll
        for (int mt = 0; mt < 2; ++mt)
            #pragma unroll
            for (int r = 0; r < 4; ++r) {
                float lv = lrow[mt][r];
                lv += __shfl_xor(lv, 1);
                lv += __shfl_xor(lv, 2);
                lv += __shfl_xor(lv, 4);
                lv += __shfl_xor(lv, 8);
                if (l15 == 0)
                    atomicAdd(lsum + (size_t)bh*TT + qw0 + mt*16 + quad*4 + r, lv);
            }
        #pragma unroll
        for (int mt = 0; mt < 2; ++mt)
            #pragma unroll
            for (int nt = 0; nt < 4; ++nt)
                #pragma unroll
                for (int r = 0; r < 4; ++r) {
                    const int row = qw0 + mt*16 + quad*4 + r;
                    const int col = h*HDD + nt*16 + l15;
                    atomicAdd(yo + (size_t)(b*TT + row)*DDE + col, o[mt][nt][r]);
                }
    }
}

// ---------------------------------------------------------------------------
// MA: linear causal attention, split-s.
// ---------------------------------------------------------------------------
__global__ __launch_bounds__(256) void attn_ma_mfma(
    const bf16_t* __restrict__ qab, const bf16_t* __restrict__ kcs,
    const bf16_t* __restrict__ etg, float* __restrict__ ma)
{
    int qt, ch;
    split_decode(39 - (int)blockIdx.x, qt, ch);
    const int h = blockIdx.y, b = blockIdx.z;
    const int tid = threadIdx.x, wave = tid >> 6, lane = tid & 63;
    const int l15 = lane & 15, quad = lane >> 4;
    const int q0 = qt * 128;
    const int bh = b * NHH + h;

    __shared__ __align__(16) unsigned short Qs[128 * 64];
    __shared__ __align__(16) unsigned short Ks[64 * 64];
    __shared__ __align__(16) unsigned short Es[64 * 64];
    __shared__ __align__(16) unsigned short Pw[4][32 * 72];
    __shared__ float Rl[128];

    stage_tile<128>(qab + (size_t)(b*TT + q0)*DDE + h*HDD, DDE, Qs, wave, lane);
    __syncthreads();
    if (tid < 128) {
        float s = 0.f;
        #pragma unroll
        for (int c = 0; c < 8; ++c) {
            bf16x8 v = *(const bf16x8*)(Qs + tid*64 + c*8);
            #pragma unroll
            for (int u = 0; u < 8; ++u) s += (float)v[u];
        }
        Rl[tid] = s;
    }
    __syncthreads();

    bf16x8 qf[2][2];
    float Rr[2][4];
    #pragma unroll
    for (int mt = 0; mt < 2; ++mt) {
        #pragma unroll
        for (int kc = 0; kc < 2; ++kc)
            qf[mt][kc] = *(const bf16x8*)(Qs + (wave*32 + mt*16 + l15)*64
                                          + ((kc*4 + quad) ^ (l15 & 7))*8);
        #pragma unroll
        for (int r = 0; r < 4; ++r)
            Rr[mt][r] = 0.5f * Rl[wave*32 + mt*16 + quad*4 + r];
    }

    f32x4 o[2][4];
    #pragma unroll
    for (int mt = 0; mt < 2; ++mt)
        #pragma unroll
        for (int nt = 0; nt < 4; ++nt) o[mt][nt] = (f32x4)0.f;

    const int qw0 = q0 + wave * 32;
    const int kt0 = ch * 8;
    const int kt1 = min(kt0 + 8, 2*qt + 2);
    bool did = false;

    for (int kt = kt0; kt < kt1; ++kt) {
        const int s0 = kt * 64;
        __syncthreads();
        stage_tile<64>(kcs + (size_t)(b*TT + s0)*DDE + h*HDD, DDE, Ks, wave, lane);
        stage_tile<64>(etg + (size_t)(bh*64)*TT + s0, TT, Es, wave, lane);
        __syncthreads();
        if (s0 > qw0 + 31) continue;
        did = true;

        f32x4 sv[2][4];
        #pragma unroll
        for (int nt = 0; nt < 4; ++nt) {
            const unsigned short* kr = Ks + (nt*16 + l15)*64;
            bf16x8 kb0 = *(const bf16x8*)(kr + ((quad    ) ^ (l15 & 7))*8);
            bf16x8 kb1 = *(const bf16x8*)(kr + ((quad + 4) ^ (l15 & 7))*8);
            #pragma unroll
            for (int mt = 0; mt < 2; ++mt) {
                f32x4 z = (f32x4)0.f;
                z = MFMA(qf[mt][0], kb0, z);
                z = MFMA(qf[mt][1], kb1, z);
                sv[mt][nt] = z;
            }
        }
        const bool domask = (s0 + 63 > qw0);
        const bool m0 = (kt == 0);
        unsigned short* pw = Pw[wave];
        #pragma unroll
        for (int mt = 0; mt < 2; ++mt)
            #pragma unroll
            for (int r = 0; r < 4; ++r)
                #pragma unroll
                for (int nt = 0; nt < 4; ++nt) {
                    const int sg = s0 + nt*16 + l15;
                    float p = sv[mt][nt][r] + Rr[mt][r];
                    if (m0 && sg == 0) p = 0.f;
                    if (domask) {
                        const int qg = qw0 + mt*16 + quad*4 + r;
                        if (sg > qg) p = 0.f;
                    }
                    pw[(mt*16 + quad*4 + r)*72 + nt*16 + l15] = bf2us((bf16_t)p);
                }
        bf16x8 pa[2][2];
        #pragma unroll
        for (int mt = 0; mt < 2; ++mt)
            #pragma unroll
            for (int sc = 0; sc < 2; ++sc)
                pa[mt][sc] = *(const bf16x8*)(pw + (mt*16 + l15)*72 + sc*32 + quad*8);
        #pragma unroll
        for (int nt = 0; nt < 4; ++nt) {
            const unsigned short* er = Es + (nt*16 + l15)*64;
            bf16x8 eb0 = *(const bf16x8*)(er + ((quad    ) ^ (l15 & 7))*8);
            bf16x8 eb1 = *(const bf16x8*)(er + ((quad + 4) ^ (l15 & 7))*8);
            #pragma unroll
            for (int mt = 0; mt < 2; ++mt) {
                o[mt][nt] = MFMA(pa[mt][0], eb0, o[mt][nt]);
                o[mt][nt] = MFMA(pa[mt][1], eb1, o[mt][nt]);
            }
        }
    }

    if (did) {
        #pragma unroll
        for (int mt = 0; mt < 2; ++mt)
            #pragma unroll
            for (int nt = 0; nt < 4; ++nt)
                #pragma unroll
                for (int r = 0; r < 4; ++r) {
                    const int row = qw0 + mt*16 + quad*4 + r;
                    const int col = h*HDD + nt*16 + l15;
                    atomicAdd(ma + (size_t)(b*TT + row)*DDE + col, o[mt][nt][r]);
                }
    }
}

// ---------------------------------------------------------------------------
// ysumb = bf16( yarb + ma )
// ---------------------------------------------------------------------------
__global__ __launch_bounds__(256) void combine(
    const bf16_t* __restrict__ yarb, const float* __restrict__ ma,
    bf16_t* __restrict__ ysumb)
{
    const size_t e = ((size_t)blockIdx.x * 256 + threadIdx.x) * 4;
    bf16x4 a = *(const bf16x4*)(yarb + e);
    float4 m = *(const float4*)(ma + e);
    bf16x4 o;
    o[0] = (bf16_t)((float)a[0] + m.x);
    o[1] = (bf16_t)((float)a[1] + m.y);
    o[2] = (bf16_t)((float)a[2] + m.z);
    o[3] = (bf16_t)((float)a[3] + m.w);
    *(bf16x4*)(ysumb + e) = o;
}

// ---------------------------------------------------------------------------
extern "C" void kernel_launch(void* const* d_in, const int* in_sizes, int n_in,
                              void* d_out, int out_size, void* d_ws, size_t ws_size,
                              hipStream_t stream)
{
    const float* x      = (const float*)d_in[0];
    const float* w_attn = (const float*)d_in[1];
    const float* b_attn = (const float*)d_in[2];
    const float* w_k2   = (const float*)d_in[3];
    const float* b_k2   = (const float*)d_in[4];
    const float* w_proj = (const float*)d_in[5];
    const float* b_proj = (const float*)d_in[6];

    const size_t NX  = (size_t)BB*TT*DDE;
    const size_t NWA = (size_t)2*DDE*DDE;
    const size_t NW  = (size_t)DDE*DDE;
    const size_t NQK = (size_t)BB*TT*2*DDE;

    bf16_t* xb   = (bf16_t*)d_ws;
    bf16_t* wab  = xb   + NX;
    bf16_t* wkb  = wab  + NWA;
    bf16_t* wpb  = wkb  + NW;
    bf16_t* qkb  = wpb  + NW;      // aliased by maf (f32) after attn_ar
    bf16_t* qab  = qkb  + NQK;
    bf16_t* kcs  = qab  + NX;
    bf16_t* vtg  = kcs  + NX;      // aliased by etg after attn_ar
    float*  yo   = (float*)(vtg + NX);  // aliased by ysumb after norm_build
    bf16_t* yarb = (bf16_t*)(yo + NX);
    float*  lsum = (float*)wab;    // aliases wab after gemm_qkk2
    float*  maf  = (float*)qkb;
    bf16_t* etg  = vtg;
    bf16_t* ysumb= (bf16_t*)yo;

    hipMemsetAsync(yo, 0, NX * sizeof(float), stream);

    const size_t NCVT = NX + NWA + NW + NW;
    cvt_all<<<NCVT / 1024, 256, 0, stream>>>(x, w_attn, w_k2, w_proj, xb);

    transpose_head<<<dim3(TT/64, NHH, BB), 256, 0, stream>>>(xb, vtg);

    const int M = BB * TT;
    gemm_qkk2<<<dim3(24, M/128), 256, 0, stream>>>(xb, wab, wkb, b_attn, b_k2,
                                                    qkb, qab, kcs);
    hipMemsetAsync(lsum, 0, (size_t)BB*NHH*TT * sizeof(float), stream);

    attn_ar_mfma<<<dim3(40, NHH, BB), 256, 0, stream>>>(qkb, vtg, yo, lsum);
    norm_build_etg<<<dim3(TT/64, NHH, BB), 256, 0, stream>>>(yo, lsum, xb, yarb, etg);

    hipMemsetAsync(maf, 0, NX * sizeof(float), stream);
    attn_ma_mfma<<<dim3(40, NHH, BB), 256, 0, stream>>>(qab, kcs, etg, maf);

    combine<<<NX / 1024, 256, 0, stream>>>(yarb, maf, ysumb);
    gemm_proj<<<dim3(DDE/128, M/128), 256, 0, stream>>>(ysumb, wpb, b_proj,
                                                        (float*)d_out, M, DDE, DDE, 2.f);
}